// Round 2
// baseline (2778.977 us; speedup 1.0000x reference)
//
#include <hip/hip_runtime.h>
#include <hip/hip_bf16.h>

// Problem constants (match reference)
#define NPTS 400000
#define NVOX 100000
#define EPSB 1e-3f

// ws layout (in floats)
#define OFF_CNT   0
#define OFF_SX    (NVOX)                 // 3*NVOX: [sx | sy | sz]
#define OFF_STATS (4*NVOX)               // 512 floats
#define OFF_V0    (4*NVOX + 512)         // NVOX*64
#define OFF_V1    (OFF_V0 + NVOX*64)     // NVOX*64
#define ZERO_FLOATS (OFF_V1 + NVOX*64)   // everything above gets zeroed
#define OFF_X     ZERO_FLOATS            // 10*NPTS, column-major [10][N]
#define OFF_W0F   (OFF_X + 10*NPTS)      // 640
#define OFF_W1F   (OFF_W0F + 640)        // 8192

// stats sub-offsets
#define S_SUM0 0
#define S_SQ0  64
#define S_SC0  128
#define S_BI0  192
#define S_SUM1 256
#define S_SQ1  320
#define S_SC1  384
#define S_BI1  448

__device__ __forceinline__ float b2f(__hip_bfloat16 h) { return __bfloat162float(h); }

// ---- K0: convert weights bf16 -> fp32 in ws ----
__global__ void k_wconv(const __hip_bfloat16* __restrict__ W0,
                        const __hip_bfloat16* __restrict__ W1,
                        float* __restrict__ W0f, float* __restrict__ W1f) {
    int t = threadIdx.x;
    for (int j = t; j < 640; j += 256)  W0f[j] = b2f(W0[j]);
    for (int j = t; j < 8192; j += 256) W1f[j] = b2f(W1[j]);
}

// ---- K1: per-voxel count + xyz sums ----
__global__ void k_vsum(const __hip_bfloat16* __restrict__ feat,
                       const int* __restrict__ inv,
                       float* __restrict__ cnt, float* __restrict__ sxyz) {
    int i = blockIdx.x * 256 + threadIdx.x;
    if (i >= NPTS) return;
    float px = b2f(feat[4*i+0]);
    float py = b2f(feat[4*i+1]);
    float pz = b2f(feat[4*i+2]);
    int v = inv[i];
    atomicAdd(&cnt[v], 1.0f);
    atomicAdd(&sxyz[v], px);
    atomicAdd(&sxyz[NVOX + v], py);
    atomicAdd(&sxyz[2*NVOX + v], pz);
}

// ---- K2: build x[10][N] + layer0 batch stats (sum, sumsq of y0 = x@W0^T) ----
__global__ void k_feat_stats0(const __hip_bfloat16* __restrict__ feat,
                              const int* __restrict__ inv,
                              const int* __restrict__ coors,
                              const float* __restrict__ cnt,
                              const float* __restrict__ sxyz,
                              const float* __restrict__ W0f,
                              float* __restrict__ xbuf,
                              float* __restrict__ stats) {
    __shared__ float bs[64], bq[64];
    int t = threadIdx.x;
    if (t < 64) { bs[t] = 0.0f; bq[t] = 0.0f; }
    __syncthreads();

    int i = blockIdx.x * 256 + t;
    bool act = (i < NPTS);
    float xv[10];
#pragma unroll
    for (int k = 0; k < 10; k++) xv[k] = 0.0f;

    if (act) {
        float px = b2f(feat[4*i+0]);
        float py = b2f(feat[4*i+1]);
        float pz = b2f(feat[4*i+2]);
        float it = b2f(feat[4*i+3]);
        int v = inv[i];
        float c_ = cnt[v];
        float mx = sxyz[v] / c_;
        float my = sxyz[NVOX + v] / c_;
        float mz = sxyz[2*NVOX + v] / c_;
        int cz = coors[4*v+1], cy = coors[4*v+2], cx = coors[4*v+3];
        float ctx = (float)cx * 0.2f + 0.1f + 0.0f;
        float cty = (float)cy * 0.2f + 0.1f - 40.0f;
        float ctz = (float)cz * 4.0f + 2.0f - 3.0f;
        xv[0] = px;       xv[1] = py;       xv[2] = pz;
        xv[3] = px - mx;  xv[4] = py - my;  xv[5] = pz - mz;
        xv[6] = px - ctx; xv[7] = py - cty; xv[8] = pz - ctz;
        xv[9] = it;
#pragma unroll
        for (int k = 0; k < 10; k++) xbuf[k*NPTS + i] = xv[k];
    }

    // per-channel batch stats (inactive lanes contribute exact zeros)
    for (int c = 0; c < 64; c++) {
        float y = 0.0f;
#pragma unroll
        for (int k = 0; k < 10; k++) y += xv[k] * W0f[c*10 + k];
        float s = y, q = y * y;
        for (int m = 32; m >= 1; m >>= 1) {
            s += __shfl_xor(s, m);
            q += __shfl_xor(q, m);
        }
        if ((t & 63) == 0) { atomicAdd(&bs[c], s); atomicAdd(&bq[c], q); }
    }
    __syncthreads();
    if (t < 64) {
        atomicAdd(&stats[S_SUM0 + t], bs[t]);
        atomicAdd(&stats[S_SQ0  + t], bq[t]);
    }
}

// ---- finalize BN: scale = gamma*rsqrt(var+eps), bias = beta - mu*scale ----
__global__ void k_finalize(const float* __restrict__ sum, const float* __restrict__ sq,
                           const __hip_bfloat16* __restrict__ gamma,
                           const __hip_bfloat16* __restrict__ beta,
                           float* __restrict__ scale, float* __restrict__ bias) {
    int c = threadIdx.x;
    if (c >= 64) return;
    float mu  = sum[c] * (1.0f / NPTS);
    float var = sq[c] * (1.0f / NPTS) - mu * mu;
    float rs  = rsqrtf(var + EPSB);
    float g   = b2f(gamma[c]) * rs;
    scale[c] = g;
    bias[c]  = b2f(beta[c]) - mu * g;
}

// ---- K3: h0 = relu(bn(y0)); segment max into v0 via uint atomicMax ----
__global__ void k_h0max(const float* __restrict__ xbuf,
                        const int* __restrict__ inv,
                        const float* __restrict__ W0f,
                        const float* __restrict__ stats,
                        float* __restrict__ v0) {
    int i = blockIdx.x * 256 + threadIdx.x;
    if (i >= NPTS) return;
    float xv[10];
#pragma unroll
    for (int k = 0; k < 10; k++) xv[k] = xbuf[k*NPTS + i];
    int v = inv[i];
    const float* sc = &stats[S_SC0];
    const float* bi = &stats[S_BI0];
    for (int c = 0; c < 64; c++) {
        float y = 0.0f;
#pragma unroll
        for (int k = 0; k < 10; k++) y += xv[k] * W0f[c*10 + k];
        float h = fmaxf(sc[c] * y + bi[c], 0.0f);
        atomicMax((unsigned int*)&v0[v*64 + c], __float_as_uint(h));
    }
}

// ---- K4: layer1 batch stats over y1 = [h0, v0[inv]] @ W1^T ----
__global__ void k_stats1(const float* __restrict__ xbuf,
                         const int* __restrict__ inv,
                         const float* __restrict__ W0f,
                         const float* __restrict__ W1f,
                         const float* __restrict__ v0,
                         float* __restrict__ stats) {
    __shared__ float bs[64], bq[64];
    int t = threadIdx.x;
    if (t < 64) { bs[t] = 0.0f; bq[t] = 0.0f; }
    __syncthreads();

    int i = blockIdx.x * 256 + t;
    bool act = (i < NPTS);

    float x1[128];
#pragma unroll
    for (int k = 0; k < 128; k++) x1[k] = 0.0f;

    if (act) {
        float xv[10];
#pragma unroll
        for (int k = 0; k < 10; k++) xv[k] = xbuf[k*NPTS + i];
        const float* sc = &stats[S_SC0];
        const float* bi = &stats[S_BI0];
#pragma unroll
        for (int c = 0; c < 64; c++) {
            float y = 0.0f;
#pragma unroll
            for (int k = 0; k < 10; k++) y += xv[k] * W0f[c*10 + k];
            x1[c] = fmaxf(sc[c] * y + bi[c], 0.0f);
        }
        int v = inv[i];
        const float4* vr = (const float4*)&v0[v*64];
#pragma unroll
        for (int j = 0; j < 16; j++) {
            float4 w = vr[j];
            x1[64 + 4*j + 0] = w.x; x1[64 + 4*j + 1] = w.y;
            x1[64 + 4*j + 2] = w.z; x1[64 + 4*j + 3] = w.w;
        }
    }

    for (int c = 0; c < 64; c++) {
        float y = 0.0f;
#pragma unroll
        for (int k = 0; k < 128; k++) y += x1[k] * W1f[c*128 + k];
        float s = y, q = y * y;
        for (int m = 32; m >= 1; m >>= 1) {
            s += __shfl_xor(s, m);
            q += __shfl_xor(q, m);
        }
        if ((t & 63) == 0) { atomicAdd(&bs[c], s); atomicAdd(&bq[c], q); }
    }
    __syncthreads();
    if (t < 64) {
        atomicAdd(&stats[S_SUM1 + t], bs[t]);
        atomicAdd(&stats[S_SQ1  + t], bq[t]);
    }
}

// ---- K5: h1 = relu(bn(y1)); segment max into v1 ----
__global__ void k_h1max(const float* __restrict__ xbuf,
                        const int* __restrict__ inv,
                        const float* __restrict__ W0f,
                        const float* __restrict__ W1f,
                        const float* __restrict__ stats,
                        const float* __restrict__ v0,
                        float* __restrict__ v1) {
    int i = blockIdx.x * 256 + threadIdx.x;
    if (i >= NPTS) return;

    float x1[128];
    {
        float xv[10];
#pragma unroll
        for (int k = 0; k < 10; k++) xv[k] = xbuf[k*NPTS + i];
        const float* sc = &stats[S_SC0];
        const float* bi = &stats[S_BI0];
#pragma unroll
        for (int c = 0; c < 64; c++) {
            float y = 0.0f;
#pragma unroll
            for (int k = 0; k < 10; k++) y += xv[k] * W0f[c*10 + k];
            x1[c] = fmaxf(sc[c] * y + bi[c], 0.0f);
        }
    }
    int v = inv[i];
    {
        const float4* vr = (const float4*)&v0[v*64];
#pragma unroll
        for (int j = 0; j < 16; j++) {
            float4 w = vr[j];
            x1[64 + 4*j + 0] = w.x; x1[64 + 4*j + 1] = w.y;
            x1[64 + 4*j + 2] = w.z; x1[64 + 4*j + 3] = w.w;
        }
    }
    const float* sc1 = &stats[S_SC1];
    const float* bi1 = &stats[S_BI1];
    for (int c = 0; c < 64; c++) {
        float y = 0.0f;
#pragma unroll
        for (int k = 0; k < 128; k++) y += x1[k] * W1f[c*128 + k];
        float h = fmaxf(sc1[c] * y + bi1[c], 0.0f);
        atomicMax((unsigned int*)&v1[v*64 + c], __float_as_uint(h));
    }
}

// ---- K6: emit output (FP32): [V*64 feats | V*4 coors] ----
// d_out is float32 (evidence: round-1 absmax == bf16(max x-coor) == 352 from
// bf16-pair aliasing). Coors are rounded through bf16 to match the bf16-cast
// numpy reference exactly.
__global__ void k_out(const float* __restrict__ v1,
                      const int* __restrict__ coors,
                      float* __restrict__ out) {
    long t = (long)blockIdx.x * 256 + threadIdx.x;
    const long nfeat = (long)NVOX * 64;
    if (t < nfeat) {
        out[t] = v1[t];
    } else if (t < nfeat + (long)NVOX * 4) {
        out[t] = b2f(__float2bfloat16((float)coors[t - nfeat]));
    }
}

extern "C" void kernel_launch(void* const* d_in, const int* in_sizes, int n_in,
                              void* d_out, int out_size, void* d_ws, size_t ws_size,
                              hipStream_t stream) {
    const __hip_bfloat16* feat = (const __hip_bfloat16*)d_in[0];
    const __hip_bfloat16* W0   = (const __hip_bfloat16*)d_in[1];
    const __hip_bfloat16* g0   = (const __hip_bfloat16*)d_in[2];
    const __hip_bfloat16* be0  = (const __hip_bfloat16*)d_in[3];
    const __hip_bfloat16* W1   = (const __hip_bfloat16*)d_in[4];
    const __hip_bfloat16* g1   = (const __hip_bfloat16*)d_in[5];
    const __hip_bfloat16* be1  = (const __hip_bfloat16*)d_in[6];
    const int* inv   = (const int*)d_in[7];
    const int* coors = (const int*)d_in[8];
    float* out = (float*)d_out;

    float* ws    = (float*)d_ws;
    float* cnt   = ws + OFF_CNT;
    float* sxyz  = ws + OFF_SX;
    float* stats = ws + OFF_STATS;
    float* v0    = ws + OFF_V0;
    float* v1    = ws + OFF_V1;
    float* xbuf  = ws + OFF_X;
    float* W0f   = ws + OFF_W0F;
    float* W1f   = ws + OFF_W1F;

    hipMemsetAsync(ws, 0, (size_t)ZERO_FLOATS * sizeof(float), stream);

    const int nblk = (NPTS + 255) / 256;
    k_wconv<<<1, 256, 0, stream>>>(W0, W1, W0f, W1f);
    k_vsum<<<nblk, 256, 0, stream>>>(feat, inv, cnt, sxyz);
    k_feat_stats0<<<nblk, 256, 0, stream>>>(feat, inv, coors, cnt, sxyz, W0f, xbuf, stats);
    k_finalize<<<1, 64, 0, stream>>>(stats + S_SUM0, stats + S_SQ0, g0, be0,
                                     stats + S_SC0, stats + S_BI0);
    k_h0max<<<nblk, 256, 0, stream>>>(xbuf, inv, W0f, stats, v0);
    k_stats1<<<nblk, 256, 0, stream>>>(xbuf, inv, W0f, W1f, v0, stats);
    k_finalize<<<1, 64, 0, stream>>>(stats + S_SUM1, stats + S_SQ1, g1, be1,
                                     stats + S_SC1, stats + S_BI1);
    k_h1max<<<nblk, 256, 0, stream>>>(xbuf, inv, W0f, W1f, stats, v0, v1);

    const long nout = (long)NVOX * 64 + (long)NVOX * 4;
    k_out<<<(int)((nout + 255) / 256), 256, 0, stream>>>(v1, coors, out);
}

// Round 3
// 2290.862 us; speedup vs baseline: 1.2131x; 1.2131x over previous
//
#include <hip/hip_runtime.h>
#include <hip/hip_bf16.h>

// Problem constants (match reference)
#define NPTS 400000
#define NVOX 100000
#define EPSB 1e-3f

// ws layout (in floats)
#define OFF_ACC4  0                      // 4*NVOX interleaved [cnt,sx,sy,sz] per voxel
#define OFF_STATS (4*NVOX)               // 512 floats
#define OFF_V0    (4*NVOX + 512)         // NVOX*64
#define OFF_V1    (OFF_V0 + NVOX*64)     // NVOX*64
#define ZERO_FLOATS (OFF_V1 + NVOX*64)   // everything above gets zeroed
#define OFF_X     ZERO_FLOATS            // 10*NPTS, column-major [10][N]
#define OFF_W0F   (OFF_X + 10*NPTS)      // 640
#define OFF_W1F   (OFF_W0F + 640)        // 8192

// stats sub-offsets
#define S_SUM0 0
#define S_SQ0  64
#define S_SC0  128
#define S_BI0  192
#define S_SUM1 256
#define S_SQ1  320
#define S_SC1  384
#define S_BI1  448

__device__ __forceinline__ float b2f(__hip_bfloat16 h) { return __bfloat162float(h); }

// ---- K0: convert weights bf16 -> fp32 in ws ----
__global__ void k_wconv(const __hip_bfloat16* __restrict__ W0,
                        const __hip_bfloat16* __restrict__ W1,
                        float* __restrict__ W0f, float* __restrict__ W1f) {
    int t = threadIdx.x;
    for (int j = t; j < 640; j += 256)  W0f[j] = b2f(W0[j]);
    for (int j = t; j < 8192; j += 256) W1f[j] = b2f(W1[j]);
}

// ---- K1: per-voxel count + xyz sums (interleaved -> 4-lane coalesced atomics) ----
__global__ void k_vsum(const __hip_bfloat16* __restrict__ feat,
                       const int* __restrict__ inv,
                       float* __restrict__ acc4) {
    long t = (long)blockIdx.x * 256 + threadIdx.x;
    int pt = (int)(t >> 2);
    int comp = (int)(t & 3);
    if (pt >= NPTS) return;
    float val = (comp == 0) ? 1.0f : b2f(feat[4 * pt + comp - 1]);
    int v = inv[pt];
    atomicAdd(&acc4[(long)v * 4 + comp], val);
}

// ---- K2: build x[10][N] + layer0 batch stats (sum, sumsq of y0 = x@W0^T) ----
__global__ void k_feat_stats0(const __hip_bfloat16* __restrict__ feat,
                              const int* __restrict__ inv,
                              const int* __restrict__ coors,
                              const float* __restrict__ acc4,
                              const float* __restrict__ W0f,
                              float* __restrict__ xbuf,
                              float* __restrict__ stats) {
    __shared__ float bs[64], bq[64];
    int t = threadIdx.x;
    if (t < 64) { bs[t] = 0.0f; bq[t] = 0.0f; }
    __syncthreads();

    int i = blockIdx.x * 256 + t;
    bool act = (i < NPTS);
    float xv[10];
#pragma unroll
    for (int k = 0; k < 10; k++) xv[k] = 0.0f;

    if (act) {
        float px = b2f(feat[4*i+0]);
        float py = b2f(feat[4*i+1]);
        float pz = b2f(feat[4*i+2]);
        float it = b2f(feat[4*i+3]);
        int v = inv[i];
        float4 a = *(const float4*)&acc4[(long)v * 4];
        float c_ = a.x;
        float mx = a.y / c_;
        float my = a.z / c_;
        float mz = a.w / c_;
        int cz = coors[4*v+1], cy = coors[4*v+2], cx = coors[4*v+3];
        float ctx = (float)cx * 0.2f + 0.1f + 0.0f;
        float cty = (float)cy * 0.2f + 0.1f - 40.0f;
        float ctz = (float)cz * 4.0f + 2.0f - 3.0f;
        xv[0] = px;       xv[1] = py;       xv[2] = pz;
        xv[3] = px - mx;  xv[4] = py - my;  xv[5] = pz - mz;
        xv[6] = px - ctx; xv[7] = py - cty; xv[8] = pz - ctz;
        xv[9] = it;
#pragma unroll
        for (int k = 0; k < 10; k++) xbuf[k*NPTS + i] = xv[k];
    }

    // per-channel batch stats (inactive lanes contribute exact zeros)
    for (int c = 0; c < 64; c++) {
        float y = 0.0f;
#pragma unroll
        for (int k = 0; k < 10; k++) y += xv[k] * W0f[c*10 + k];
        float s = y, q = y * y;
        for (int m = 32; m >= 1; m >>= 1) {
            s += __shfl_xor(s, m);
            q += __shfl_xor(q, m);
        }
        if ((t & 63) == 0) { atomicAdd(&bs[c], s); atomicAdd(&bq[c], q); }
    }
    __syncthreads();
    if (t < 64) {
        atomicAdd(&stats[S_SUM0 + t], bs[t]);
        atomicAdd(&stats[S_SQ0  + t], bq[t]);
    }
}

// ---- finalize BN: scale = gamma*rsqrt(var+eps), bias = beta - mu*scale ----
__global__ void k_finalize(const float* __restrict__ sum, const float* __restrict__ sq,
                           const __hip_bfloat16* __restrict__ gamma,
                           const __hip_bfloat16* __restrict__ beta,
                           float* __restrict__ scale, float* __restrict__ bias) {
    int c = threadIdx.x;
    if (c >= 64) return;
    float mu  = sum[c] * (1.0f / NPTS);
    float var = sq[c] * (1.0f / NPTS) - mu * mu;
    float rs  = rsqrtf(var + EPSB);
    float g   = b2f(gamma[c]) * rs;
    scale[c] = g;
    bias[c]  = b2f(beta[c]) - mu * g;
}

// ---- K3: h0 = relu(bn(y0)); transpose via LDS; COALESCED atomicMax into v0 ----
// Phase A: lane = point, compute h[64] (W0/BN via wave-uniform scalar loads).
// Phase B: 4 rounds through a 64x65 LDS tile; lane = channel, one point per
// wave-instruction -> 64 lanes hit v0[v*64+0..63] (4 cache lines, not 64).
__global__ void k_h0max(const float* __restrict__ xbuf,
                        const int* __restrict__ inv,
                        const float* __restrict__ W0f,
                        const float* __restrict__ stats,
                        float* __restrict__ v0) {
    __shared__ float hs[64 * 65];
    int t = threadIdx.x, w = t >> 6, l = t & 63;
    long base = (long)blockIdx.x * 256;
    int i = (int)(base + w * 64 + l);
    bool act = (i < NPTS);

    float h[64];
    if (act) {
        float xv[10];
#pragma unroll
        for (int k = 0; k < 10; k++) xv[k] = xbuf[k*NPTS + i];
        const float* sc = &stats[S_SC0];
        const float* bi = &stats[S_BI0];
#pragma unroll
        for (int c = 0; c < 64; c++) {
            float y = 0.0f;
#pragma unroll
            for (int k = 0; k < 10; k++) y += xv[k] * W0f[c*10 + k];
            h[c] = fmaxf(sc[c] * y + bi[c], 0.0f);
        }
    }

    for (int r = 0; r < 4; r++) {
        __syncthreads();
        if (w == r && act) {
#pragma unroll
            for (int c = 0; c < 64; c++) hs[l * 65 + c] = h[c];
        }
        __syncthreads();
#pragma unroll
        for (int j = 0; j < 16; j++) {
            int p = w * 16 + j;                 // point within the round's tile
            long gi = base + r * 64 + p;
            if (gi < NPTS) {
                float hv = hs[p * 65 + l];
                int vv = inv[gi];               // wave-uniform
                atomicMax((unsigned int*)&v0[(long)vv * 64 + l], __float_as_uint(hv));
            }
        }
    }
}

// ---- K4: layer1 batch stats over y1 = [h0, v0[inv]] @ W1^T (reg x1, scalar W1) ----
__global__ void k_stats1(const float* __restrict__ xbuf,
                         const int* __restrict__ inv,
                         const float* __restrict__ W0f,
                         const float* __restrict__ W1f,
                         const float* __restrict__ v0,
                         float* __restrict__ stats) {
    __shared__ float bs[64], bq[64];
    int t = threadIdx.x;
    if (t < 64) { bs[t] = 0.0f; bq[t] = 0.0f; }
    __syncthreads();

    int i = blockIdx.x * 256 + t;
    bool act = (i < NPTS);

    float x1[128];
#pragma unroll
    for (int k = 0; k < 128; k++) x1[k] = 0.0f;

    if (act) {
        float xv[10];
#pragma unroll
        for (int k = 0; k < 10; k++) xv[k] = xbuf[k*NPTS + i];
        const float* sc = &stats[S_SC0];
        const float* bi = &stats[S_BI0];
#pragma unroll
        for (int c = 0; c < 64; c++) {
            float y = 0.0f;
#pragma unroll
            for (int k = 0; k < 10; k++) y += xv[k] * W0f[c*10 + k];
            x1[c] = fmaxf(sc[c] * y + bi[c], 0.0f);
        }
        int v = inv[i];
        const float4* vr = (const float4*)&v0[(long)v * 64];
#pragma unroll
        for (int j = 0; j < 16; j++) {
            float4 wv = vr[j];
            x1[64 + 4*j + 0] = wv.x; x1[64 + 4*j + 1] = wv.y;
            x1[64 + 4*j + 2] = wv.z; x1[64 + 4*j + 3] = wv.w;
        }
    }

    for (int c = 0; c < 64; c++) {
        float y = 0.0f;
#pragma unroll
        for (int k = 0; k < 128; k++) y += x1[k] * W1f[c*128 + k];
        float s = y, q = y * y;
        for (int m = 32; m >= 1; m >>= 1) {
            s += __shfl_xor(s, m);
            q += __shfl_xor(q, m);
        }
        if ((t & 63) == 0) { atomicAdd(&bs[c], s); atomicAdd(&bq[c], q); }
    }
    __syncthreads();
    if (t < 64) {
        atomicAdd(&stats[S_SUM1 + t], bs[t]);
        atomicAdd(&stats[S_SQ1  + t], bq[t]);
    }
}

// ---- K5: h1 = relu(bn(y1)); transpose via LDS; COALESCED atomicMax into v1 ----
__global__ void k_h1max(const float* __restrict__ xbuf,
                        const int* __restrict__ inv,
                        const float* __restrict__ W0f,
                        const float* __restrict__ W1f,
                        const float* __restrict__ stats,
                        const float* __restrict__ v0,
                        float* __restrict__ v1) {
    __shared__ float hs[64 * 65];
    int t = threadIdx.x, w = t >> 6, l = t & 63;
    long base = (long)blockIdx.x * 256;
    int i = (int)(base + w * 64 + l);
    bool act = (i < NPTS);

    float h[64];
    if (act) {
        float x1[128];
        {
            float xv[10];
#pragma unroll
            for (int k = 0; k < 10; k++) xv[k] = xbuf[k*NPTS + i];
            const float* sc = &stats[S_SC0];
            const float* bi = &stats[S_BI0];
#pragma unroll
            for (int c = 0; c < 64; c++) {
                float y = 0.0f;
#pragma unroll
                for (int k = 0; k < 10; k++) y += xv[k] * W0f[c*10 + k];
                x1[c] = fmaxf(sc[c] * y + bi[c], 0.0f);
            }
        }
        int v = inv[i];
        {
            const float4* vr = (const float4*)&v0[(long)v * 64];
#pragma unroll
            for (int j = 0; j < 16; j++) {
                float4 wv = vr[j];
                x1[64 + 4*j + 0] = wv.x; x1[64 + 4*j + 1] = wv.y;
                x1[64 + 4*j + 2] = wv.z; x1[64 + 4*j + 3] = wv.w;
            }
        }
        const float* sc1 = &stats[S_SC1];
        const float* bi1 = &stats[S_BI1];
        for (int c = 0; c < 64; c++) {
            float y = 0.0f;
#pragma unroll
            for (int k = 0; k < 128; k++) y += x1[k] * W1f[c*128 + k];
            h[c] = fmaxf(sc1[c] * y + bi1[c], 0.0f);
        }
    }

    for (int r = 0; r < 4; r++) {
        __syncthreads();
        if (w == r && act) {
#pragma unroll
            for (int c = 0; c < 64; c++) hs[l * 65 + c] = h[c];
        }
        __syncthreads();
#pragma unroll
        for (int j = 0; j < 16; j++) {
            int p = w * 16 + j;
            long gi = base + r * 64 + p;
            if (gi < NPTS) {
                float hv = hs[p * 65 + l];
                int vv = inv[gi];
                atomicMax((unsigned int*)&v1[(long)vv * 64 + l], __float_as_uint(hv));
            }
        }
    }
}

// ---- K6: emit output (FP32): [V*64 feats | V*4 coors] ----
__global__ void k_out(const float* __restrict__ v1,
                      const int* __restrict__ coors,
                      float* __restrict__ out) {
    long t = (long)blockIdx.x * 256 + threadIdx.x;
    const long nfeat = (long)NVOX * 64;
    if (t < nfeat) {
        out[t] = v1[t];
    } else if (t < nfeat + (long)NVOX * 4) {
        out[t] = b2f(__float2bfloat16((float)coors[t - nfeat]));
    }
}

extern "C" void kernel_launch(void* const* d_in, const int* in_sizes, int n_in,
                              void* d_out, int out_size, void* d_ws, size_t ws_size,
                              hipStream_t stream) {
    const __hip_bfloat16* feat = (const __hip_bfloat16*)d_in[0];
    const __hip_bfloat16* W0   = (const __hip_bfloat16*)d_in[1];
    const __hip_bfloat16* g0   = (const __hip_bfloat16*)d_in[2];
    const __hip_bfloat16* be0  = (const __hip_bfloat16*)d_in[3];
    const __hip_bfloat16* W1   = (const __hip_bfloat16*)d_in[4];
    const __hip_bfloat16* g1   = (const __hip_bfloat16*)d_in[5];
    const __hip_bfloat16* be1  = (const __hip_bfloat16*)d_in[6];
    const int* inv   = (const int*)d_in[7];
    const int* coors = (const int*)d_in[8];
    float* out = (float*)d_out;

    float* ws    = (float*)d_ws;
    float* acc4  = ws + OFF_ACC4;
    float* stats = ws + OFF_STATS;
    float* v0    = ws + OFF_V0;
    float* v1    = ws + OFF_V1;
    float* xbuf  = ws + OFF_X;
    float* W0f   = ws + OFF_W0F;
    float* W1f   = ws + OFF_W1F;

    hipMemsetAsync(ws, 0, (size_t)ZERO_FLOATS * sizeof(float), stream);

    const int nblk = (NPTS + 255) / 256;
    k_wconv<<<1, 256, 0, stream>>>(W0, W1, W0f, W1f);
    k_vsum<<<(4 * NPTS + 255) / 256, 256, 0, stream>>>(feat, inv, acc4);
    k_feat_stats0<<<nblk, 256, 0, stream>>>(feat, inv, coors, acc4, W0f, xbuf, stats);
    k_finalize<<<1, 64, 0, stream>>>(stats + S_SUM0, stats + S_SQ0, g0, be0,
                                     stats + S_SC0, stats + S_BI0);
    k_h0max<<<nblk, 256, 0, stream>>>(xbuf, inv, W0f, stats, v0);
    k_stats1<<<nblk, 256, 0, stream>>>(xbuf, inv, W0f, W1f, v0, stats);
    k_finalize<<<1, 64, 0, stream>>>(stats + S_SUM1, stats + S_SQ1, g1, be1,
                                     stats + S_SC1, stats + S_BI1);
    k_h1max<<<nblk, 256, 0, stream>>>(xbuf, inv, W0f, W1f, stats, v0, v1);

    const long nout = (long)NVOX * 64 + (long)NVOX * 4;
    k_out<<<(int)((nout + 255) / 256), 256, 0, stream>>>(v1, coors, out);
}

// Round 4
// 1124.962 us; speedup vs baseline: 2.4703x; 2.0364x over previous
//
#include <hip/hip_runtime.h>
#include <hip/hip_bf16.h>

// Problem constants (match reference)
#define NPTS 400000
#define NVOX 100000
#define EPSB 1e-3f

// ws layout (in floats)
#define OFF_ACC4  0                      // 4*NVOX interleaved [cnt,sx,sy,sz] per voxel
#define OFF_STATS (4*NVOX)               // 512 floats
#define OFF_V0    (4*NVOX + 512)         // NVOX*64
#define OFF_V1    (OFF_V0 + NVOX*64)     // NVOX*64
#define ZERO_FLOATS (OFF_V1 + NVOX*64)   // everything above gets zeroed
#define OFF_X     ZERO_FLOATS            // 10*NPTS, column-major [10][N]
#define OFF_W0F   (OFF_X + 10*NPTS)      // 640  (row-major [c][10])
#define OFF_W1T   (OFF_W0F + 640)        // 8192 (TRANSPOSED [k][64])

// stats sub-offsets
#define S_SUM0 0
#define S_SQ0  64
#define S_SC0  128
#define S_BI0  192
#define S_SUM1 256
#define S_SQ1  320
#define S_SC1  384
#define S_BI1  448

// LDS tile stride (pad 128 -> 132: keeps float4 alignment, breaks pow2 banks)
#define XT_LD 132

__device__ __forceinline__ float b2f(__hip_bfloat16 h) { return __bfloat162float(h); }

// ---- K0: convert weights bf16 -> fp32; W1 transposed to [k][64] ----
__global__ void k_wconv(const __hip_bfloat16* __restrict__ W0,
                        const __hip_bfloat16* __restrict__ W1,
                        float* __restrict__ W0f, float* __restrict__ W1T) {
    int t = threadIdx.x;
    for (int j = t; j < 640; j += 256)  W0f[j] = b2f(W0[j]);
    for (int j = t; j < 8192; j += 256) {
        int k = j >> 6, c = j & 63;          // dest index j = k*64 + c
        W1T[j] = b2f(W1[c * 128 + k]);       // src row-major [c][128]
    }
}

// ---- K1: per-voxel count + xyz sums (interleaved -> 4-lane coalesced atomics) ----
__global__ void k_vsum(const __hip_bfloat16* __restrict__ feat,
                       const int* __restrict__ inv,
                       float* __restrict__ acc4) {
    long t = (long)blockIdx.x * 256 + threadIdx.x;
    int pt = (int)(t >> 2);
    int comp = (int)(t & 3);
    if (pt >= NPTS) return;
    float val = (comp == 0) ? 1.0f : b2f(feat[4 * pt + comp - 1]);
    int v = inv[pt];
    atomicAdd(&acc4[(long)v * 4 + comp], val);
}

// ---- K2: build x[10][N] + layer0 batch stats (sum, sumsq of y0 = x@W0^T) ----
__global__ void k_feat_stats0(const __hip_bfloat16* __restrict__ feat,
                              const int* __restrict__ inv,
                              const int* __restrict__ coors,
                              const float* __restrict__ acc4,
                              const float* __restrict__ W0f,
                              float* __restrict__ xbuf,
                              float* __restrict__ stats) {
    __shared__ float bs[64], bq[64];
    int t = threadIdx.x;
    if (t < 64) { bs[t] = 0.0f; bq[t] = 0.0f; }
    __syncthreads();

    int i = blockIdx.x * 256 + t;
    bool act = (i < NPTS);
    float xv[10];
#pragma unroll
    for (int k = 0; k < 10; k++) xv[k] = 0.0f;

    if (act) {
        float px = b2f(feat[4*i+0]);
        float py = b2f(feat[4*i+1]);
        float pz = b2f(feat[4*i+2]);
        float it = b2f(feat[4*i+3]);
        int v = inv[i];
        float4 a = *(const float4*)&acc4[(long)v * 4];
        float c_ = a.x;
        float mx = a.y / c_;
        float my = a.z / c_;
        float mz = a.w / c_;
        int cz = coors[4*v+1], cy = coors[4*v+2], cx = coors[4*v+3];
        float ctx = (float)cx * 0.2f + 0.1f + 0.0f;
        float cty = (float)cy * 0.2f + 0.1f - 40.0f;
        float ctz = (float)cz * 4.0f + 2.0f - 3.0f;
        xv[0] = px;       xv[1] = py;       xv[2] = pz;
        xv[3] = px - mx;  xv[4] = py - my;  xv[5] = pz - mz;
        xv[6] = px - ctx; xv[7] = py - cty; xv[8] = pz - ctz;
        xv[9] = it;
#pragma unroll
        for (int k = 0; k < 10; k++) xbuf[k*NPTS + i] = xv[k];
    }

    for (int c = 0; c < 64; c++) {
        float y = 0.0f;
#pragma unroll
        for (int k = 0; k < 10; k++) y += xv[k] * W0f[c*10 + k];
        float s = y, q = y * y;
        for (int m = 32; m >= 1; m >>= 1) {
            s += __shfl_xor(s, m);
            q += __shfl_xor(q, m);
        }
        if ((t & 63) == 0) { atomicAdd(&bs[c], s); atomicAdd(&bq[c], q); }
    }
    __syncthreads();
    if (t < 64) {
        atomicAdd(&stats[S_SUM0 + t], bs[t]);
        atomicAdd(&stats[S_SQ0  + t], bq[t]);
    }
}

// ---- finalize BN: scale = gamma*rsqrt(var+eps), bias = beta - mu*scale ----
__global__ void k_finalize(const float* __restrict__ sum, const float* __restrict__ sq,
                           const __hip_bfloat16* __restrict__ gamma,
                           const __hip_bfloat16* __restrict__ beta,
                           float* __restrict__ scale, float* __restrict__ bias) {
    int c = threadIdx.x;
    if (c >= 64) return;
    float mu  = sum[c] * (1.0f / NPTS);
    float var = sq[c] * (1.0f / NPTS) - mu * mu;
    float rs  = rsqrtf(var + EPSB);
    float g   = b2f(gamma[c]) * rs;
    scale[c] = g;
    bias[c]  = b2f(beta[c]) - mu * g;
}

// ---- K3: h0 = relu(bn(y0)); tile-structured, acc[16]/thread (no spill);
//      LDS transpose -> coalesced atomicMax into v0 ----
__global__ __launch_bounds__(256, 2)
void k_h0max(const float* __restrict__ xbuf,
             const int* __restrict__ inv,
             const float* __restrict__ W0f,
             const float* __restrict__ stats,
             float* __restrict__ v0) {
    __shared__ float ht[64 * 68];          // [p][c], stride 68
    int t = threadIdx.x, w = t >> 6, l = t & 63;
    int cw = __builtin_amdgcn_readfirstlane(w * 16);
    long blk0 = (long)blockIdx.x * 256;

    for (int tile = 0; tile < 4; tile++) {
        long base = blk0 + tile * 64;
        bool act = (base + l) < NPTS;
        float xv[10];
#pragma unroll
        for (int k = 0; k < 10; k++)
            xv[k] = act ? xbuf[(long)k * NPTS + base + l] : 0.0f;
#pragma unroll
        for (int j = 0; j < 16; j++) {
            int c = cw + j;
            float y = 0.0f;
#pragma unroll
            for (int k = 0; k < 10; k++) y += xv[k] * W0f[c*10 + k];
            ht[l * 68 + c] = fmaxf(stats[S_SC0 + c] * y + stats[S_BI0 + c], 0.0f);
        }
        __syncthreads();
        // lane = channel; 16 points per wave; 64 lanes hit one contiguous v0 row
#pragma unroll
        for (int j = 0; j < 16; j++) {
            int p = w * 16 + j;
            long gi = base + p;
            if (gi < NPTS) {
                float hv = ht[p * 68 + l];
                int vv = inv[gi];
                atomicMax((unsigned int*)&v0[(long)vv * 64 + l], __float_as_uint(hv));
            }
        }
        __syncthreads();
    }
}

// ---- shared staging for layer-1 tiles: xt[p][0..128) = [h0 | v0[inv]] ----
__device__ __forceinline__ void stage_x1_tile(float* __restrict__ xt,
                                              const float* __restrict__ xbuf,
                                              const int* __restrict__ inv,
                                              const float* __restrict__ W0f,
                                              const float* __restrict__ stats,
                                              const float* __restrict__ v0,
                                              long base, int t, int w, int l, int cw) {
    // h0 part: lane = point, wave = 16-channel slice
    {
        bool act = (base + l) < NPTS;
        float xv[10];
#pragma unroll
        for (int k = 0; k < 10; k++)
            xv[k] = act ? xbuf[(long)k * NPTS + base + l] : 0.0f;
#pragma unroll
        for (int j = 0; j < 16; j++) {
            int c = cw + j;
            float y = 0.0f;
#pragma unroll
            for (int k = 0; k < 10; k++) y += xv[k] * W0f[c*10 + k];
            float h = fmaxf(stats[S_SC0 + c] * y + stats[S_BI0 + c], 0.0f);
            xt[l * XT_LD + c] = act ? h : 0.0f;
        }
    }
    // v0 gather: 4 lanes per point -> each 256B row fetched contiguously
    {
        int p = t >> 2, q = t & 3;
        long gi = base + p;
        float* dst = &xt[p * XT_LD + 64 + q * 16];
        if (gi < NPTS) {
            int vv = inv[gi];
            const float4* src = (const float4*)&v0[(long)vv * 64 + q * 16];
#pragma unroll
            for (int j = 0; j < 4; j++) ((float4*)dst)[j] = src[j];
        } else {
            float4 z = {0.f, 0.f, 0.f, 0.f};
#pragma unroll
            for (int j = 0; j < 4; j++) ((float4*)dst)[j] = z;
        }
    }
}

// ---- K4: layer-1 GEMM + batch stats (sum, sumsq of y1), tiled, no spill ----
__global__ __launch_bounds__(256, 2)
void k_gemm1_stats(const float* __restrict__ xbuf,
                   const int* __restrict__ inv,
                   const float* __restrict__ W0f,
                   const float* __restrict__ W1T,
                   const float* __restrict__ v0,
                   float* __restrict__ stats) {
    __shared__ float xt[64 * XT_LD];
    int t = threadIdx.x, w = t >> 6, l = t & 63;
    int cw = __builtin_amdgcn_readfirstlane(w * 16);
    long blk0 = (long)blockIdx.x * 256;

    float ssum[16], ssq[16];
#pragma unroll
    for (int j = 0; j < 16; j++) { ssum[j] = 0.0f; ssq[j] = 0.0f; }

    for (int tile = 0; tile < 4; tile++) {
        long base = blk0 + tile * 64;
        stage_x1_tile(xt, xbuf, inv, W0f, stats, v0, base, t, w, l, cw);
        __syncthreads();

        float acc[16];
#pragma unroll
        for (int j = 0; j < 16; j++) acc[j] = 0.0f;
        for (int k = 0; k < 128; k += 4) {
            float4 x4 = *(const float4*)&xt[l * XT_LD + k];
#pragma unroll
            for (int j = 0; j < 16; j++) {
                acc[j] += x4.x * W1T[(k+0)*64 + cw + j];
                acc[j] += x4.y * W1T[(k+1)*64 + cw + j];
                acc[j] += x4.z * W1T[(k+2)*64 + cw + j];
                acc[j] += x4.w * W1T[(k+3)*64 + cw + j];
            }
        }
#pragma unroll
        for (int j = 0; j < 16; j++) { ssum[j] += acc[j]; ssq[j] += acc[j]*acc[j]; }
        __syncthreads();
    }

#pragma unroll
    for (int j = 0; j < 16; j++) {
        float s = ssum[j], q = ssq[j];
        for (int m = 32; m >= 1; m >>= 1) {
            s += __shfl_xor(s, m);
            q += __shfl_xor(q, m);
        }
        if (l == 0) {
            atomicAdd(&stats[S_SUM1 + cw + j], s);
            atomicAdd(&stats[S_SQ1  + cw + j], q);
        }
    }
}

// ---- K5: layer-1 GEMM + BN + ReLU; LDS transpose -> coalesced atomicMax v1 ----
__global__ __launch_bounds__(256, 2)
void k_gemm1_apply(const float* __restrict__ xbuf,
                   const int* __restrict__ inv,
                   const float* __restrict__ W0f,
                   const float* __restrict__ W1T,
                   const float* __restrict__ stats,
                   const float* __restrict__ v0,
                   float* __restrict__ v1) {
    __shared__ float xt[64 * XT_LD];
    int t = threadIdx.x, w = t >> 6, l = t & 63;
    int cw = __builtin_amdgcn_readfirstlane(w * 16);
    long blk0 = (long)blockIdx.x * 256;

    for (int tile = 0; tile < 4; tile++) {
        long base = blk0 + tile * 64;
        stage_x1_tile(xt, xbuf, inv, W0f, stats, v0, base, t, w, l, cw);
        __syncthreads();

        float acc[16];
#pragma unroll
        for (int j = 0; j < 16; j++) acc[j] = 0.0f;
        for (int k = 0; k < 128; k += 4) {
            float4 x4 = *(const float4*)&xt[l * XT_LD + k];
#pragma unroll
            for (int j = 0; j < 16; j++) {
                acc[j] += x4.x * W1T[(k+0)*64 + cw + j];
                acc[j] += x4.y * W1T[(k+1)*64 + cw + j];
                acc[j] += x4.z * W1T[(k+2)*64 + cw + j];
                acc[j] += x4.w * W1T[(k+3)*64 + cw + j];
            }
        }
        __syncthreads();   // all GEMM reads of xt done before overwrite
#pragma unroll
        for (int j = 0; j < 16; j++) {
            int c = cw + j;
            xt[l * XT_LD + c] = fmaxf(stats[S_SC1 + c] * acc[j] + stats[S_BI1 + c], 0.0f);
        }
        __syncthreads();
        // lane = channel; coalesced atomicMax (one contiguous v1 row per instr)
#pragma unroll
        for (int j = 0; j < 16; j++) {
            int p = w * 16 + j;
            long gi = base + p;
            if (gi < NPTS) {
                float hv = xt[p * XT_LD + l];
                int vv = inv[gi];
                atomicMax((unsigned int*)&v1[(long)vv * 64 + l], __float_as_uint(hv));
            }
        }
        __syncthreads();
    }
}

// ---- K6: emit output (FP32): [V*64 feats | V*4 coors] ----
__global__ void k_out(const float* __restrict__ v1,
                      const int* __restrict__ coors,
                      float* __restrict__ out) {
    long t = (long)blockIdx.x * 256 + threadIdx.x;
    const long nfeat = (long)NVOX * 64;
    if (t < nfeat) {
        out[t] = v1[t];
    } else if (t < nfeat + (long)NVOX * 4) {
        out[t] = b2f(__float2bfloat16((float)coors[t - nfeat]));
    }
}

extern "C" void kernel_launch(void* const* d_in, const int* in_sizes, int n_in,
                              void* d_out, int out_size, void* d_ws, size_t ws_size,
                              hipStream_t stream) {
    const __hip_bfloat16* feat = (const __hip_bfloat16*)d_in[0];
    const __hip_bfloat16* W0   = (const __hip_bfloat16*)d_in[1];
    const __hip_bfloat16* g0   = (const __hip_bfloat16*)d_in[2];
    const __hip_bfloat16* be0  = (const __hip_bfloat16*)d_in[3];
    const __hip_bfloat16* W1   = (const __hip_bfloat16*)d_in[4];
    const __hip_bfloat16* g1   = (const __hip_bfloat16*)d_in[5];
    const __hip_bfloat16* be1  = (const __hip_bfloat16*)d_in[6];
    const int* inv   = (const int*)d_in[7];
    const int* coors = (const int*)d_in[8];
    float* out = (float*)d_out;

    float* ws    = (float*)d_ws;
    float* acc4  = ws + OFF_ACC4;
    float* stats = ws + OFF_STATS;
    float* v0    = ws + OFF_V0;
    float* v1    = ws + OFF_V1;
    float* xbuf  = ws + OFF_X;
    float* W0f   = ws + OFF_W0F;
    float* W1T   = ws + OFF_W1T;

    hipMemsetAsync(ws, 0, (size_t)ZERO_FLOATS * sizeof(float), stream);

    const int nblk  = (NPTS + 255) / 256;   // 1563 (point-per-thread kernels)
    const int nblkT = (NPTS + 255) / 256;   // tile kernels: 256 points/block

    k_wconv<<<1, 256, 0, stream>>>(W0, W1, W0f, W1T);
    k_vsum<<<(4 * NPTS + 255) / 256, 256, 0, stream>>>(feat, inv, acc4);
    k_feat_stats0<<<nblk, 256, 0, stream>>>(feat, inv, coors, acc4, W0f, xbuf, stats);
    k_finalize<<<1, 64, 0, stream>>>(stats + S_SUM0, stats + S_SQ0, g0, be0,
                                     stats + S_SC0, stats + S_BI0);
    k_h0max<<<nblkT, 256, 0, stream>>>(xbuf, inv, W0f, stats, v0);
    k_gemm1_stats<<<nblkT, 256, 0, stream>>>(xbuf, inv, W0f, W1T, v0, stats);
    k_finalize<<<1, 64, 0, stream>>>(stats + S_SUM1, stats + S_SQ1, g1, be1,
                                     stats + S_SC1, stats + S_BI1);
    k_gemm1_apply<<<nblkT, 256, 0, stream>>>(xbuf, inv, W0f, W1T, stats, v0, v1);

    const long nout = (long)NVOX * 64 + (long)NVOX * 4;
    k_out<<<(int)((nout + 255) / 256), 256, 0, stream>>>(v1, coors, out);
}

// Round 5
// 519.653 us; speedup vs baseline: 5.3478x; 2.1648x over previous
//
#include <hip/hip_runtime.h>
#include <hip/hip_bf16.h>

// Problem constants (match reference)
#define NPTS 400000
#define NVOX 100000
#define EPSB 1e-3f

// ws layout (in floats)
#define OFF_ACC4  0                      // 4*NVOX interleaved [cnt,sx,sy,sz]
#define OFF_STATS (4*NVOX)               // 512 floats
#define OFF_V0    (4*NVOX + 512)         // NVOX*64
#define OFF_V1    (OFF_V0 + NVOX*64)     // NVOX*64
#define ZERO_FLOATS (OFF_V1 + NVOX*64)   // zeroed region
#define OFF_X     ZERO_FLOATS            // 10*NPTS, column-major [10][N]
#define OFF_W0F   (OFF_X + 10*NPTS)      // 640 (row-major [c][10])
#define OFF_W1B   (OFF_W0F + 640)        // 4096 floats = 8192 bf16 frag-packed

// stats sub-offsets
#define S_SUM0 0
#define S_SQ0  64
#define S_SC0  128
#define S_BI0  192
#define S_SUM1 256
#define S_SQ1  320
#define S_SC1  384
#define S_BI1  448

#define XTB_LD 136   // bf16 units per point row (128 + 8 pad; 272B: 16B-aligned, 2-way banks)
#define HT_LD  68

typedef __bf16 bf16x8 __attribute__((ext_vector_type(8)));
typedef float  f32x4  __attribute__((ext_vector_type(4)));

__device__ __forceinline__ float b2f(__hip_bfloat16 h) { return __bfloat162float(h); }
__device__ __forceinline__ unsigned short bf16u(float f) {
    __hip_bfloat16 h = __float2bfloat16(f);
    return __builtin_bit_cast(unsigned short, h);
}

// ---- K0: W0 -> fp32; W1 -> bf16 MFMA B-fragment order ----
// w1b flat idx f = ((ct*4 + ks)*64 + lane)*8 + j
//   ch = ct*16 + (lane&15); k = ks*32 + ((lane>>4)&3)*8 + j; src = W1[ch*128 + k]
__global__ void k_wconv(const __hip_bfloat16* __restrict__ W0,
                        const __hip_bfloat16* __restrict__ W1,
                        float* __restrict__ W0f, unsigned short* __restrict__ w1b) {
    int t = threadIdx.x;
    for (int j = t; j < 640; j += 256) W0f[j] = b2f(W0[j]);
    for (int f = t; f < 8192; f += 256) {
        int j  = f & 7;
        int l  = (f >> 3) & 63;
        int ks = (f >> 9) & 3;
        int ct = f >> 11;
        int ch = ct * 16 + (l & 15);
        int k  = ks * 32 + ((l >> 4) & 3) * 8 + j;
        w1b[f] = __builtin_bit_cast(unsigned short, W1[ch * 128 + k]);
    }
}

// ---- K1: per-voxel count + xyz sums (4-lane coalesced atomics) ----
__global__ void k_vsum(const __hip_bfloat16* __restrict__ feat,
                       const int* __restrict__ inv,
                       float* __restrict__ acc4) {
    long t = (long)blockIdx.x * 256 + threadIdx.x;
    int pt = (int)(t >> 2);
    int comp = (int)(t & 3);
    if (pt >= NPTS) return;
    float val = (comp == 0) ? 1.0f : b2f(feat[4 * pt + comp - 1]);
    int v = inv[pt];
    atomicAdd(&acc4[(long)v * 4 + comp], val);
}

// ---- K2: build x[10][N] + layer0 batch stats ----
__global__ void k_feat_stats0(const __hip_bfloat16* __restrict__ feat,
                              const int* __restrict__ inv,
                              const int* __restrict__ coors,
                              const float* __restrict__ acc4,
                              const float* __restrict__ W0f,
                              float* __restrict__ xbuf,
                              float* __restrict__ stats) {
    __shared__ float bs[64], bq[64];
    int t = threadIdx.x;
    if (t < 64) { bs[t] = 0.0f; bq[t] = 0.0f; }
    __syncthreads();

    int i = blockIdx.x * 256 + t;
    bool act = (i < NPTS);
    float xv[10];
#pragma unroll
    for (int k = 0; k < 10; k++) xv[k] = 0.0f;

    if (act) {
        float px = b2f(feat[4*i+0]);
        float py = b2f(feat[4*i+1]);
        float pz = b2f(feat[4*i+2]);
        float it = b2f(feat[4*i+3]);
        int v = inv[i];
        float4 a = *(const float4*)&acc4[(long)v * 4];
        float c_ = a.x;
        float mx = a.y / c_;
        float my = a.z / c_;
        float mz = a.w / c_;
        int cz = coors[4*v+1], cy = coors[4*v+2], cx = coors[4*v+3];
        float ctx = (float)cx * 0.2f + 0.1f + 0.0f;
        float cty = (float)cy * 0.2f + 0.1f - 40.0f;
        float ctz = (float)cz * 4.0f + 2.0f - 3.0f;
        xv[0] = px;       xv[1] = py;       xv[2] = pz;
        xv[3] = px - mx;  xv[4] = py - my;  xv[5] = pz - mz;
        xv[6] = px - ctx; xv[7] = py - cty; xv[8] = pz - ctz;
        xv[9] = it;
#pragma unroll
        for (int k = 0; k < 10; k++) xbuf[k*NPTS + i] = xv[k];
    }

    for (int c = 0; c < 64; c++) {
        float y = 0.0f;
#pragma unroll
        for (int k = 0; k < 10; k++) y += xv[k] * W0f[c*10 + k];
        float s = y, q = y * y;
        for (int m = 32; m >= 1; m >>= 1) {
            s += __shfl_xor(s, m);
            q += __shfl_xor(q, m);
        }
        if ((t & 63) == 0) { atomicAdd(&bs[c], s); atomicAdd(&bq[c], q); }
    }
    __syncthreads();
    if (t < 64) {
        atomicAdd(&stats[S_SUM0 + t], bs[t]);
        atomicAdd(&stats[S_SQ0  + t], bq[t]);
    }
}

// ---- finalize BN ----
__global__ void k_finalize(const float* __restrict__ sum, const float* __restrict__ sq,
                           const __hip_bfloat16* __restrict__ gamma,
                           const __hip_bfloat16* __restrict__ beta,
                           float* __restrict__ scale, float* __restrict__ bias) {
    int c = threadIdx.x;
    if (c >= 64) return;
    float mu  = sum[c] * (1.0f / NPTS);
    float var = sq[c] * (1.0f / NPTS) - mu * mu;
    float rs  = rsqrtf(var + EPSB);
    float g   = b2f(gamma[c]) * rs;
    scale[c] = g;
    bias[c]  = b2f(beta[c]) - mu * g;
}

// ---- K3: h0 = relu(bn(y0)); LDS transpose -> coalesced atomicMax into v0 ----
__global__ __launch_bounds__(256, 2)
void k_h0max(const float* __restrict__ xbuf,
             const int* __restrict__ inv,
             const float* __restrict__ W0f,
             const float* __restrict__ stats,
             float* __restrict__ v0) {
    __shared__ float ht[64 * HT_LD];
    int t = threadIdx.x, w = t >> 6, l = t & 63;
    int cw = __builtin_amdgcn_readfirstlane(w * 16);
    long blk0 = (long)blockIdx.x * 256;

    for (int tile = 0; tile < 4; tile++) {
        long base = blk0 + tile * 64;
        if (base >= NPTS) break;
        bool act = (base + l) < NPTS;
        float xv[10];
#pragma unroll
        for (int k = 0; k < 10; k++)
            xv[k] = act ? xbuf[(long)k * NPTS + base + l] : 0.0f;
#pragma unroll
        for (int j = 0; j < 16; j++) {
            int c = cw + j;
            float y = 0.0f;
#pragma unroll
            for (int k = 0; k < 10; k++) y += xv[k] * W0f[c*10 + k];
            ht[l * HT_LD + c] = fmaxf(stats[S_SC0 + c] * y + stats[S_BI0 + c], 0.0f);
        }
        __syncthreads();
#pragma unroll
        for (int j = 0; j < 16; j++) {
            int p = w * 16 + j;
            long gi = base + p;
            if (gi < NPTS) {
                float hv = ht[p * HT_LD + l];
                int vv = inv[gi];
                atomicMax((unsigned int*)&v0[(long)vv * 64 + l], __float_as_uint(hv));
            }
        }
        __syncthreads();
    }
}

// ---- stage one 64-pt x1 tile as bf16 [pt][k], k in [0,128), row stride XTB_LD ----
__device__ __forceinline__ void stage_x1_bf16(unsigned short* __restrict__ xtb,
                                              const float* __restrict__ xbuf,
                                              const int* __restrict__ inv,
                                              const float* __restrict__ W0f,
                                              const float* __restrict__ stats,
                                              const float* __restrict__ v0,
                                              long base, int t, int w, int l) {
    int cw = w * 16;
    // h0 half: lane = point, wave = 16-channel slice; pack pairs -> b32 writes
    {
        bool act = (base + l) < NPTS;
        float xv[10];
#pragma unroll
        for (int k = 0; k < 10; k++)
            xv[k] = act ? xbuf[(long)k * NPTS + base + l] : 0.0f;
#pragma unroll
        for (int jj = 0; jj < 8; jj++) {
            int c0 = cw + 2 * jj, c1 = c0 + 1;
            float ya = 0.0f, yb = 0.0f;
#pragma unroll
            for (int k = 0; k < 10; k++) {
                ya += xv[k] * W0f[c0*10 + k];
                yb += xv[k] * W0f[c1*10 + k];
            }
            float ha = act ? fmaxf(stats[S_SC0 + c0] * ya + stats[S_BI0 + c0], 0.0f) : 0.0f;
            float hb = act ? fmaxf(stats[S_SC0 + c1] * yb + stats[S_BI0 + c1], 0.0f) : 0.0f;
            unsigned int pk = (unsigned int)bf16u(ha) | ((unsigned int)bf16u(hb) << 16);
            *(unsigned int*)&xtb[l * XTB_LD + c0] = pk;
        }
    }
    // v0 half: 4 lanes per point; each fetches 4 float4 (contiguous row chunk)
    {
        int p = t >> 2, q = t & 3;
        long gi = base + p;
        if (gi < NPTS) {
            int vv = inv[gi];
            const float4* src = (const float4*)&v0[(long)vv * 64 + q * 16];
#pragma unroll
            for (int u = 0; u < 4; u++) {
                float4 f4 = src[u];
                ushort4 s4 = { bf16u(f4.x), bf16u(f4.y), bf16u(f4.z), bf16u(f4.w) };
                *(ushort4*)&xtb[p * XTB_LD + 64 + q * 16 + 4 * u] = s4;
            }
        } else {
            ushort4 z = {0, 0, 0, 0};
#pragma unroll
            for (int u = 0; u < 4; u++)
                *(ushort4*)&xtb[p * XTB_LD + 64 + q * 16 + 4 * u] = z;
        }
    }
}

// ---- K4: layer-1 MFMA GEMM + batch stats (no y1 materialization) ----
// wave w = 16-channel tile; B-frags (W1) preloaded once into VGPRs.
__global__ __launch_bounds__(256, 4)
void k_mfma_stats(const float* __restrict__ xbuf,
                  const int* __restrict__ inv,
                  const float* __restrict__ W0f,
                  const unsigned short* __restrict__ w1b,
                  const float* __restrict__ v0,
                  float* __restrict__ stats) {
    __shared__ unsigned short xtb[64 * XTB_LD];
    int t = threadIdx.x, w = t >> 6, l = t & 63;
    int quad = l >> 4, lm = l & 15;

    bf16x8 bfrag[4];
    const uint4* wf = (const uint4*)w1b;
#pragma unroll
    for (int ks = 0; ks < 4; ks++)
        bfrag[ks] = __builtin_bit_cast(bf16x8, wf[(w * 4 + ks) * 64 + l]);

    float ssum = 0.0f, ssq = 0.0f;
    long blk0 = (long)blockIdx.x * 256;

    for (int tile = 0; tile < 4; tile++) {
        long base = blk0 + tile * 64;
        if (base >= NPTS) break;
        stage_x1_bf16(xtb, xbuf, inv, W0f, stats, v0, base, t, w, l);
        __syncthreads();

        f32x4 acc[4];
#pragma unroll
        for (int pg = 0; pg < 4; pg++) acc[pg] = (f32x4){0.f, 0.f, 0.f, 0.f};
#pragma unroll
        for (int ks = 0; ks < 4; ks++) {
#pragma unroll
            for (int pg = 0; pg < 4; pg++) {
                const uint4* ap = (const uint4*)&xtb[(pg * 16 + lm) * XTB_LD + ks * 32 + quad * 8];
                bf16x8 a = __builtin_bit_cast(bf16x8, *ap);
                acc[pg] = __builtin_amdgcn_mfma_f32_16x16x32_bf16(a, bfrag[ks], acc[pg], 0, 0, 0);
            }
        }
#pragma unroll
        for (int pg = 0; pg < 4; pg++) {
#pragma unroll
            for (int r = 0; r < 4; r++) {
                float y = acc[pg][r];
                ssum += y; ssq += y * y;
            }
        }
        __syncthreads();
    }

    // lanes sharing (l&15) hold the same channel: reduce across quads
    ssum += __shfl_xor(ssum, 16); ssq += __shfl_xor(ssq, 16);
    ssum += __shfl_xor(ssum, 32); ssq += __shfl_xor(ssq, 32);
    if (l < 16) {
        atomicAdd(&stats[S_SUM1 + w * 16 + lm], ssum);
        atomicAdd(&stats[S_SQ1  + w * 16 + lm], ssq);
    }
}

// ---- K5: layer-1 MFMA GEMM + BN + ReLU -> LDS transpose -> coalesced atomicMax v1 ----
__global__ __launch_bounds__(256, 4)
void k_mfma_apply(const float* __restrict__ xbuf,
                  const int* __restrict__ inv,
                  const float* __restrict__ W0f,
                  const unsigned short* __restrict__ w1b,
                  const float* __restrict__ stats,
                  const float* __restrict__ v0,
                  float* __restrict__ v1) {
    __shared__ unsigned short xtb[64 * XTB_LD];
    __shared__ float ht[64 * HT_LD];
    int t = threadIdx.x, w = t >> 6, l = t & 63;
    int quad = l >> 4, lm = l & 15;

    bf16x8 bfrag[4];
    const uint4* wf = (const uint4*)w1b;
#pragma unroll
    for (int ks = 0; ks < 4; ks++)
        bfrag[ks] = __builtin_bit_cast(bf16x8, wf[(w * 4 + ks) * 64 + l]);

    float sc1 = stats[S_SC1 + w * 16 + lm];
    float bi1 = stats[S_BI1 + w * 16 + lm];
    long blk0 = (long)blockIdx.x * 256;

    for (int tile = 0; tile < 4; tile++) {
        long base = blk0 + tile * 64;
        if (base >= NPTS) break;
        stage_x1_bf16(xtb, xbuf, inv, W0f, stats, v0, base, t, w, l);
        __syncthreads();

        f32x4 acc[4];
#pragma unroll
        for (int pg = 0; pg < 4; pg++) acc[pg] = (f32x4){0.f, 0.f, 0.f, 0.f};
#pragma unroll
        for (int ks = 0; ks < 4; ks++) {
#pragma unroll
            for (int pg = 0; pg < 4; pg++) {
                const uint4* ap = (const uint4*)&xtb[(pg * 16 + lm) * XTB_LD + ks * 32 + quad * 8];
                bf16x8 a = __builtin_bit_cast(bf16x8, *ap);
                acc[pg] = __builtin_amdgcn_mfma_f32_16x16x32_bf16(a, bfrag[ks], acc[pg], 0, 0, 0);
            }
        }
        // D layout: row(pt within 16) = quad*4 + r, col(ch within 16) = lm
#pragma unroll
        for (int pg = 0; pg < 4; pg++) {
#pragma unroll
            for (int r = 0; r < 4; r++) {
                float h = fmaxf(sc1 * acc[pg][r] + bi1, 0.0f);
                ht[(pg * 16 + quad * 4 + r) * HT_LD + w * 16 + lm] = h;
            }
        }
        __syncthreads();
#pragma unroll
        for (int j = 0; j < 16; j++) {
            int p = w * 16 + j;
            long gi = base + p;
            if (gi < NPTS) {
                float hv = ht[p * HT_LD + l];
                int vv = inv[gi];
                atomicMax((unsigned int*)&v1[(long)vv * 64 + l], __float_as_uint(hv));
            }
        }
        __syncthreads();
    }
}

// ---- K6: emit output (FP32): [V*64 feats | V*4 coors] ----
__global__ void k_out(const float* __restrict__ v1,
                      const int* __restrict__ coors,
                      float* __restrict__ out) {
    long t = (long)blockIdx.x * 256 + threadIdx.x;
    const long nfeat = (long)NVOX * 64;
    if (t < nfeat) {
        out[t] = v1[t];
    } else if (t < nfeat + (long)NVOX * 4) {
        out[t] = b2f(__float2bfloat16((float)coors[t - nfeat]));
    }
}

extern "C" void kernel_launch(void* const* d_in, const int* in_sizes, int n_in,
                              void* d_out, int out_size, void* d_ws, size_t ws_size,
                              hipStream_t stream) {
    const __hip_bfloat16* feat = (const __hip_bfloat16*)d_in[0];
    const __hip_bfloat16* W0   = (const __hip_bfloat16*)d_in[1];
    const __hip_bfloat16* g0   = (const __hip_bfloat16*)d_in[2];
    const __hip_bfloat16* be0  = (const __hip_bfloat16*)d_in[3];
    const __hip_bfloat16* W1   = (const __hip_bfloat16*)d_in[4];
    const __hip_bfloat16* g1   = (const __hip_bfloat16*)d_in[5];
    const __hip_bfloat16* be1  = (const __hip_bfloat16*)d_in[6];
    const int* inv   = (const int*)d_in[7];
    const int* coors = (const int*)d_in[8];
    float* out = (float*)d_out;

    float* ws    = (float*)d_ws;
    float* acc4  = ws + OFF_ACC4;
    float* stats = ws + OFF_STATS;
    float* v0    = ws + OFF_V0;
    float* v1    = ws + OFF_V1;
    float* xbuf  = ws + OFF_X;
    float* W0f   = ws + OFF_W0F;
    unsigned short* w1b = (unsigned short*)(ws + OFF_W1B);

    hipMemsetAsync(ws, 0, (size_t)ZERO_FLOATS * sizeof(float), stream);

    const int nblk  = (NPTS + 255) / 256;

    k_wconv<<<1, 256, 0, stream>>>(W0, W1, W0f, w1b);
    k_vsum<<<(4 * NPTS + 255) / 256, 256, 0, stream>>>(feat, inv, acc4);
    k_feat_stats0<<<nblk, 256, 0, stream>>>(feat, inv, coors, acc4, W0f, xbuf, stats);
    k_finalize<<<1, 64, 0, stream>>>(stats + S_SUM0, stats + S_SQ0, g0, be0,
                                     stats + S_SC0, stats + S_BI0);
    k_h0max<<<nblk, 256, 0, stream>>>(xbuf, inv, W0f, stats, v0);
    k_mfma_stats<<<nblk, 256, 0, stream>>>(xbuf, inv, W0f, w1b, v0, stats);
    k_finalize<<<1, 64, 0, stream>>>(stats + S_SUM1, stats + S_SQ1, g1, be1,
                                     stats + S_SC1, stats + S_BI1);
    k_mfma_apply<<<nblk, 256, 0, stream>>>(xbuf, inv, W0f, w1b, stats, v0, v1);

    const long nout = (long)NVOX * 64 + (long)NVOX * 4;
    k_out<<<(int)((nout + 255) / 256), 256, 0, stream>>>(v1, coors, out);
}

// Round 6
// 464.156 us; speedup vs baseline: 5.9872x; 1.1196x over previous
//
#include <hip/hip_runtime.h>
#include <hip/hip_bf16.h>

// Problem constants (match reference)
#define NPTS 400000
#define NVOX 100000
#define EPSB 1e-3f

// ws layout (in floats)
#define OFF_ACC4  0                      // 4*NVOX interleaved [cnt,sx,sy,sz]
#define OFF_STATS (4*NVOX)               // 512 floats
#define OFF_V0    (4*NVOX + 512)         // NVOX*64 (h0 max, plain uint keys, h0>=0)
#define OFF_Y1M   (OFF_V0 + NVOX*64)     // NVOX*64 (raw y1 max, orderable-uint keys)
#define ZERO_FLOATS (OFF_Y1M + NVOX*64)  // zeroed region
#define OFF_X     ZERO_FLOATS            // 10*NPTS, column-major [10][N]
#define OFF_W0F   (OFF_X + 10*NPTS)      // 640 (row-major [c][10])
#define OFF_W1B   (OFF_W0F + 640)        // 4096 floats = 8192 bf16 frag-packed

// stats sub-offsets
#define S_SUM0 0
#define S_SQ0  64
#define S_SC0  128
#define S_BI0  192
#define S_SUM1 256
#define S_SQ1  320
#define S_SC1  384
#define S_BI1  448

#define XTB_LD 136   // bf16 units per point row (128 + 8 pad)
#define HT_LD  68

typedef __bf16 bf16x8 __attribute__((ext_vector_type(8)));
typedef float  f32x4  __attribute__((ext_vector_type(4)));

__device__ __forceinline__ float b2f(__hip_bfloat16 h) { return __bfloat162float(h); }
__device__ __forceinline__ unsigned short bf16u(float f) {
    __hip_bfloat16 h = __float2bfloat16(f);
    return __builtin_bit_cast(unsigned short, h);
}
// orderable-uint encode/decode for signed-float atomicMax (key 0 < any real key)
__device__ __forceinline__ unsigned int fkey(float f) {
    unsigned int u = __float_as_uint(f);
    return (u & 0x80000000u) ? ~u : (u | 0x80000000u);
}
__device__ __forceinline__ float funkey(unsigned int k) {
    unsigned int u = (k & 0x80000000u) ? (k & 0x7FFFFFFFu) : ~k;
    return __uint_as_float(u);
}

// ---- K0: W0 -> fp32; W1 -> bf16 MFMA B-fragment order ----
__global__ void k_wconv(const __hip_bfloat16* __restrict__ W0,
                        const __hip_bfloat16* __restrict__ W1,
                        float* __restrict__ W0f, unsigned short* __restrict__ w1b) {
    int t = threadIdx.x;
    for (int j = t; j < 640; j += 256) W0f[j] = b2f(W0[j]);
    for (int f = t; f < 8192; f += 256) {
        int j  = f & 7;
        int l  = (f >> 3) & 63;
        int ks = (f >> 9) & 3;
        int ct = f >> 11;
        int ch = ct * 16 + (l & 15);
        int k  = ks * 32 + ((l >> 4) & 3) * 8 + j;
        w1b[f] = __builtin_bit_cast(unsigned short, W1[ch * 128 + k]);
    }
}

// ---- K1: per-voxel count + xyz sums (4-lane coalesced atomics) ----
__global__ void k_vsum(const __hip_bfloat16* __restrict__ feat,
                       const int* __restrict__ inv,
                       float* __restrict__ acc4) {
    long t = (long)blockIdx.x * 256 + threadIdx.x;
    int pt = (int)(t >> 2);
    int comp = (int)(t & 3);
    if (pt >= NPTS) return;
    float val = (comp == 0) ? 1.0f : b2f(feat[4 * pt + comp - 1]);
    int v = inv[pt];
    atomicAdd(&acc4[(long)v * 4 + comp], val);
}

// ---- K2: build x[10][N] + layer0 batch stats ----
__global__ void k_feat_stats0(const __hip_bfloat16* __restrict__ feat,
                              const int* __restrict__ inv,
                              const int* __restrict__ coors,
                              const float* __restrict__ acc4,
                              const float* __restrict__ W0f,
                              float* __restrict__ xbuf,
                              float* __restrict__ stats) {
    __shared__ float bs[64], bq[64];
    int t = threadIdx.x;
    if (t < 64) { bs[t] = 0.0f; bq[t] = 0.0f; }
    __syncthreads();

    int i = blockIdx.x * 256 + t;
    bool act = (i < NPTS);
    float xv[10];
#pragma unroll
    for (int k = 0; k < 10; k++) xv[k] = 0.0f;

    if (act) {
        float px = b2f(feat[4*i+0]);
        float py = b2f(feat[4*i+1]);
        float pz = b2f(feat[4*i+2]);
        float it = b2f(feat[4*i+3]);
        int v = inv[i];
        float4 a = *(const float4*)&acc4[(long)v * 4];
        float c_ = a.x;
        float mx = a.y / c_;
        float my = a.z / c_;
        float mz = a.w / c_;
        int cz = coors[4*v+1], cy = coors[4*v+2], cx = coors[4*v+3];
        float ctx = (float)cx * 0.2f + 0.1f + 0.0f;
        float cty = (float)cy * 0.2f + 0.1f - 40.0f;
        float ctz = (float)cz * 4.0f + 2.0f - 3.0f;
        xv[0] = px;       xv[1] = py;       xv[2] = pz;
        xv[3] = px - mx;  xv[4] = py - my;  xv[5] = pz - mz;
        xv[6] = px - ctx; xv[7] = py - cty; xv[8] = pz - ctz;
        xv[9] = it;
#pragma unroll
        for (int k = 0; k < 10; k++) xbuf[k*NPTS + i] = xv[k];
    }

    for (int c = 0; c < 64; c++) {
        float y = 0.0f;
#pragma unroll
        for (int k = 0; k < 10; k++) y += xv[k] * W0f[c*10 + k];
        float s = y, q = y * y;
        for (int m = 32; m >= 1; m >>= 1) {
            s += __shfl_xor(s, m);
            q += __shfl_xor(q, m);
        }
        if ((t & 63) == 0) { atomicAdd(&bs[c], s); atomicAdd(&bq[c], q); }
    }
    __syncthreads();
    if (t < 64) {
        atomicAdd(&stats[S_SUM0 + t], bs[t]);
        atomicAdd(&stats[S_SQ0  + t], bq[t]);
    }
}

// ---- finalize BN ----
__global__ void k_finalize(const float* __restrict__ sum, const float* __restrict__ sq,
                           const __hip_bfloat16* __restrict__ gamma,
                           const __hip_bfloat16* __restrict__ beta,
                           float* __restrict__ scale, float* __restrict__ bias) {
    int c = threadIdx.x;
    if (c >= 64) return;
    float mu  = sum[c] * (1.0f / NPTS);
    float var = sq[c] * (1.0f / NPTS) - mu * mu;
    float rs  = rsqrtf(var + EPSB);
    float g   = b2f(gamma[c]) * rs;
    scale[c] = g;
    bias[c]  = b2f(beta[c]) - mu * g;
}

// ---- K3: h0 = relu(bn(y0)); LDS transpose -> coalesced atomicMax into v0 ----
__global__ __launch_bounds__(256, 2)
void k_h0max(const float* __restrict__ xbuf,
             const int* __restrict__ inv,
             const float* __restrict__ W0f,
             const float* __restrict__ stats,
             float* __restrict__ v0) {
    __shared__ float ht[64 * HT_LD];
    int t = threadIdx.x, w = t >> 6, l = t & 63;
    int cw = __builtin_amdgcn_readfirstlane(w * 16);
    long blk0 = (long)blockIdx.x * 256;

    for (int tile = 0; tile < 4; tile++) {
        long base = blk0 + tile * 64;
        if (base >= NPTS) break;
        bool act = (base + l) < NPTS;
        float xv[10];
#pragma unroll
        for (int k = 0; k < 10; k++)
            xv[k] = act ? xbuf[(long)k * NPTS + base + l] : 0.0f;
#pragma unroll
        for (int j = 0; j < 16; j++) {
            int c = cw + j;
            float y = 0.0f;
#pragma unroll
            for (int k = 0; k < 10; k++) y += xv[k] * W0f[c*10 + k];
            ht[l * HT_LD + c] = fmaxf(stats[S_SC0 + c] * y + stats[S_BI0 + c], 0.0f);
        }
        __syncthreads();
#pragma unroll
        for (int j = 0; j < 16; j++) {
            int p = w * 16 + j;
            long gi = base + p;
            if (gi < NPTS) {
                float hv = ht[p * HT_LD + l];
                int vv = inv[gi];
                atomicMax((unsigned int*)&v0[(long)vv * 64 + l], __float_as_uint(hv));
            }
        }
        __syncthreads();
    }
}

// ---- stage one 64-pt x1 tile as bf16 [pt][k] ----
__device__ __forceinline__ void stage_x1_bf16(unsigned short* __restrict__ xtb,
                                              const float* __restrict__ xbuf,
                                              const int* __restrict__ inv,
                                              const float* __restrict__ W0f,
                                              const float* __restrict__ stats,
                                              const float* __restrict__ v0,
                                              long base, int t, int w, int l) {
    int cw = w * 16;
    {
        bool act = (base + l) < NPTS;
        float xv[10];
#pragma unroll
        for (int k = 0; k < 10; k++)
            xv[k] = act ? xbuf[(long)k * NPTS + base + l] : 0.0f;
#pragma unroll
        for (int jj = 0; jj < 8; jj++) {
            int c0 = cw + 2 * jj, c1 = c0 + 1;
            float ya = 0.0f, yb = 0.0f;
#pragma unroll
            for (int k = 0; k < 10; k++) {
                ya += xv[k] * W0f[c0*10 + k];
                yb += xv[k] * W0f[c1*10 + k];
            }
            float ha = act ? fmaxf(stats[S_SC0 + c0] * ya + stats[S_BI0 + c0], 0.0f) : 0.0f;
            float hb = act ? fmaxf(stats[S_SC0 + c1] * yb + stats[S_BI0 + c1], 0.0f) : 0.0f;
            unsigned int pk = (unsigned int)bf16u(ha) | ((unsigned int)bf16u(hb) << 16);
        *(unsigned int*)&xtb[l * XTB_LD + c0] = pk;
        }
    }
    {
        int p = t >> 2, q = t & 3;
        long gi = base + p;
        if (gi < NPTS) {
            int vv = inv[gi];
            const float4* src = (const float4*)&v0[(long)vv * 64 + q * 16];
#pragma unroll
            for (int u = 0; u < 4; u++) {
                float4 f4 = src[u];
                ushort4 s4 = { bf16u(f4.x), bf16u(f4.y), bf16u(f4.z), bf16u(f4.w) };
                *(ushort4*)&xtb[p * XTB_LD + 64 + q * 16 + 4 * u] = s4;
            }
        } else {
            ushort4 z = {0, 0, 0, 0};
#pragma unroll
            for (int u = 0; u < 4; u++)
                *(ushort4*)&xtb[p * XTB_LD + 64 + q * 16 + 4 * u] = z;
        }
    }
}

// ---- K4: layer-1 MFMA GEMM: batch stats + RAW-y1 segment max (single pass).
// BN1 is strictly increasing (gamma>0) and ReLU monotone, so
// segment_max(relu(bn(y1))) == relu(bn(segment_max(y1))) — bit-exact.
// y1 can be negative -> orderable-uint keys in y1m. ----
__global__ __launch_bounds__(256, 4)
void k_mfma_stats(const float* __restrict__ xbuf,
                  const int* __restrict__ inv,
                  const float* __restrict__ W0f,
                  const unsigned short* __restrict__ w1b,
                  const float* __restrict__ v0,
                  float* __restrict__ stats,
                  unsigned int* __restrict__ y1m) {
    __shared__ unsigned short xtb[64 * XTB_LD];
    __shared__ float ht[64 * HT_LD];
    int t = threadIdx.x, w = t >> 6, l = t & 63;
    int quad = l >> 4, lm = l & 15;

    bf16x8 bfrag[4];
    const uint4* wf = (const uint4*)w1b;
#pragma unroll
    for (int ks = 0; ks < 4; ks++)
        bfrag[ks] = __builtin_bit_cast(bf16x8, wf[(w * 4 + ks) * 64 + l]);

    float ssum = 0.0f, ssq = 0.0f;
    long blk0 = (long)blockIdx.x * 256;

    for (int tile = 0; tile < 4; tile++) {
        long base = blk0 + tile * 64;
        if (base >= NPTS) break;
        stage_x1_bf16(xtb, xbuf, inv, W0f, stats, v0, base, t, w, l);
        __syncthreads();

        f32x4 acc[4];
#pragma unroll
        for (int pg = 0; pg < 4; pg++) acc[pg] = (f32x4){0.f, 0.f, 0.f, 0.f};
#pragma unroll
        for (int ks = 0; ks < 4; ks++) {
#pragma unroll
            for (int pg = 0; pg < 4; pg++) {
                const uint4* ap = (const uint4*)&xtb[(pg * 16 + lm) * XTB_LD + ks * 32 + quad * 8];
                bf16x8 a = __builtin_bit_cast(bf16x8, *ap);
                acc[pg] = __builtin_amdgcn_mfma_f32_16x16x32_bf16(a, bfrag[ks], acc[pg], 0, 0, 0);
            }
        }
        // stats + write raw y1 to ht (D layout: row = quad*4+r, col = lm)
#pragma unroll
        for (int pg = 0; pg < 4; pg++) {
#pragma unroll
            for (int r = 0; r < 4; r++) {
                float y = acc[pg][r];
                ssum += y; ssq += y * y;
                ht[(pg * 16 + quad * 4 + r) * HT_LD + w * 16 + lm] = y;
            }
        }
        __syncthreads();
        // lane = channel; coalesced atomicMax of orderable keys
#pragma unroll
        for (int j = 0; j < 16; j++) {
            int p = w * 16 + j;
            long gi = base + p;
            if (gi < NPTS) {
                unsigned int key = fkey(ht[p * HT_LD + l]);
                int vv = inv[gi];
                atomicMax(&y1m[(long)vv * 64 + l], key);
            }
        }
        __syncthreads();
    }

    ssum += __shfl_xor(ssum, 16); ssq += __shfl_xor(ssq, 16);
    ssum += __shfl_xor(ssum, 32); ssq += __shfl_xor(ssq, 32);
    if (l < 16) {
        atomicAdd(&stats[S_SUM1 + w * 16 + lm], ssum);
        atomicAdd(&stats[S_SQ1  + w * 16 + lm], ssq);
    }
}

// ---- K5: emit output: feats = relu(bn1(decode(y1max))), then bf16-rounded coors ----
__global__ void k_out(const unsigned int* __restrict__ y1m,
                      const float* __restrict__ stats,
                      const int* __restrict__ coors,
                      float* __restrict__ out) {
    long t = (long)blockIdx.x * 256 + threadIdx.x;
    const long nfeat = (long)NVOX * 64;
    if (t < nfeat) {
        int c = (int)(t & 63);
        float y = funkey(y1m[t]);
        out[t] = fmaxf(stats[S_SC1 + c] * y + stats[S_BI1 + c], 0.0f);
    } else if (t < nfeat + (long)NVOX * 4) {
        out[t] = b2f(__float2bfloat16((float)coors[t - nfeat]));
    }
}

extern "C" void kernel_launch(void* const* d_in, const int* in_sizes, int n_in,
                              void* d_out, int out_size, void* d_ws, size_t ws_size,
                              hipStream_t stream) {
    const __hip_bfloat16* feat = (const __hip_bfloat16*)d_in[0];
    const __hip_bfloat16* W0   = (const __hip_bfloat16*)d_in[1];
    const __hip_bfloat16* g0   = (const __hip_bfloat16*)d_in[2];
    const __hip_bfloat16* be0  = (const __hip_bfloat16*)d_in[3];
    const __hip_bfloat16* W1   = (const __hip_bfloat16*)d_in[4];
    const __hip_bfloat16* g1   = (const __hip_bfloat16*)d_in[5];
    const __hip_bfloat16* be1  = (const __hip_bfloat16*)d_in[6];
    const int* inv   = (const int*)d_in[7];
    const int* coors = (const int*)d_in[8];
    float* out = (float*)d_out;

    float* ws    = (float*)d_ws;
    float* acc4  = ws + OFF_ACC4;
    float* stats = ws + OFF_STATS;
    float* v0    = ws + OFF_V0;
    unsigned int* y1m = (unsigned int*)(ws + OFF_Y1M);
    float* xbuf  = ws + OFF_X;
    float* W0f   = ws + OFF_W0F;
    unsigned short* w1b = (unsigned short*)(ws + OFF_W1B);

    hipMemsetAsync(ws, 0, (size_t)ZERO_FLOATS * sizeof(float), stream);

    const int nblk = (NPTS + 255) / 256;

    k_wconv<<<1, 256, 0, stream>>>(W0, W1, W0f, w1b);
    k_vsum<<<(4 * NPTS + 255) / 256, 256, 0, stream>>>(feat, inv, acc4);
    k_feat_stats0<<<nblk, 256, 0, stream>>>(feat, inv, coors, acc4, W0f, xbuf, stats);
    k_finalize<<<1, 64, 0, stream>>>(stats + S_SUM0, stats + S_SQ0, g0, be0,
                                     stats + S_SC0, stats + S_BI0);
    k_h0max<<<nblk, 256, 0, stream>>>(xbuf, inv, W0f, stats, v0);
    k_mfma_stats<<<nblk, 256, 0, stream>>>(xbuf, inv, W0f, w1b, v0, stats, y1m);
    k_finalize<<<1, 64, 0, stream>>>(stats + S_SUM1, stats + S_SQ1, g1, be1,
                                     stats + S_SC1, stats + S_BI1);

    const long nout = (long)NVOX * 64 + (long)NVOX * 4;
    k_out<<<(int)((nout + 255) / 256), 256, 0, stream>>>(y1m, stats, coors, out);
}

// Round 7
// 411.804 us; speedup vs baseline: 6.7483x; 1.1271x over previous
//
#include <hip/hip_runtime.h>
#include <hip/hip_bf16.h>

// Problem constants (match reference)
#define NPTS 400000          // == 6250 * 64 exactly (no tile tails)
#define NVOX 100000
#define EPSB 1e-3f
#define NTILE 6250

// ws layout (in floats)
#define OFF_ACC4  0                       // 4*NVOX interleaved [cnt,sx,sy,sz]
#define OFF_GRAM  (4*NVOX)                // 72: sx[10] + sxx[55] (padded)
#define OFF_STATS (OFF_GRAM + 72)         // 256: sc0|bi0|sc1|bi1
#define OFF_P1    (OFF_STATS + 256)       // 32 slots * 128 (layer1 sum|sq partials)
#define OFF_V0    (OFF_P1 + 4096)         // NVOX*64 (h0 max, plain uint keys, h0>=0)
#define OFF_Y1M   (OFF_V0 + NVOX*64)      // NVOX*64 (raw y1 max, orderable keys)
#define ZERO_FLOATS (OFF_Y1M + NVOX*64)
#define OFF_X     ZERO_FLOATS             // 10*NPTS column-major [10][N]
#define OFF_W0F   (OFF_X + 10*NPTS)       // 640 (row-major [c][10])
#define OFF_W1B   (OFF_W0F + 640)         // 4096 floats = 8192 bf16 frag-packed

// stats sub-offsets
#define S_SC0 0
#define S_BI0 64
#define S_SC1 128
#define S_BI1 192

#define XTB_LD 136   // bf16/row: 16B-aligned, odd word-quad stride -> balanced b128 banks
#define HT_LD  65    // float/row: odd stride -> conflict-free transpose writes

#define GBLK 782     // feat_gram grid (2-3 pts/thread)

typedef __bf16 bf16x8 __attribute__((ext_vector_type(8)));
typedef float  f32x4  __attribute__((ext_vector_type(4)));

__device__ __forceinline__ float b2f(__hip_bfloat16 h) { return __bfloat162float(h); }
__device__ __forceinline__ float bfbits2f(unsigned short u) {
    return __uint_as_float((unsigned int)u << 16);
}
__device__ __forceinline__ unsigned short bf16u(float f) {
    __hip_bfloat16 h = __float2bfloat16(f);
    return __builtin_bit_cast(unsigned short, h);
}
// orderable-uint encode/decode for signed-float atomicMax (key 0 < any real key)
__device__ __forceinline__ unsigned int fkey(float f) {
    unsigned int u = __float_as_uint(f);
    return (u & 0x80000000u) ? ~u : (u | 0x80000000u);
}
__device__ __forceinline__ float funkey(unsigned int k) {
    unsigned int u = (k & 0x80000000u) ? (k & 0x7FFFFFFFu) : ~k;
    return __uint_as_float(u);
}

// ---- K0: W0 -> fp32; W1 -> bf16 MFMA B-fragment order ----
__global__ void k_wconv(const __hip_bfloat16* __restrict__ W0,
                        const __hip_bfloat16* __restrict__ W1,
                        float* __restrict__ W0f, unsigned short* __restrict__ w1b) {
    int t = threadIdx.x;
    for (int j = t; j < 640; j += 256) W0f[j] = b2f(W0[j]);
    for (int f = t; f < 8192; f += 256) {
        int j  = f & 7;
        int l  = (f >> 3) & 63;
        int ks = (f >> 9) & 3;
        int ct = f >> 11;
        int ch = ct * 16 + (l & 15);
        int k  = ks * 32 + ((l >> 4) & 3) * 8 + j;
        w1b[f] = __builtin_bit_cast(unsigned short, W1[ch * 128 + k]);
    }
}

// ---- K1: per-voxel count + xyz sums (4-lane coalesced atomics) ----
__global__ void k_vsum(const __hip_bfloat16* __restrict__ feat,
                       const int* __restrict__ inv,
                       float* __restrict__ acc4) {
    long t = (long)blockIdx.x * 256 + threadIdx.x;
    int pt = (int)(t >> 2);
    int comp = (int)(t & 3);
    if (pt >= NPTS) return;
    float val = (comp == 0) ? 1.0f : b2f(feat[4 * pt + comp - 1]);
    int v = inv[pt];
    atomicAdd(&acc4[(long)v * 4 + comp], val);
}

// ---- K2: build x[10][N]; accumulate Gram stats (sx[10], sxx[55]) in registers ----
// Layer-0 batch stats via sum(y0_c) = W0_c . sx ; sum(y0_c^2) = W0_c^T Sxx W0_c.
__global__ __launch_bounds__(256, 4)
void k_feat_gram(const __hip_bfloat16* __restrict__ feat,
                 const int* __restrict__ inv,
                 const int* __restrict__ coors,
                 const float* __restrict__ acc4,
                 float* __restrict__ xbuf,
                 float* __restrict__ gram) {
    __shared__ float gs[72];
    int t = threadIdx.x;
    if (t < 72) gs[t] = 0.0f;
    __syncthreads();

    float sx[10], sxx[55];
#pragma unroll
    for (int a = 0; a < 10; a++) sx[a] = 0.0f;
#pragma unroll
    for (int a = 0; a < 55; a++) sxx[a] = 0.0f;

    for (long i = (long)blockIdx.x * 256 + t; i < NPTS; i += (long)GBLK * 256) {
        ushort4 f4 = *(const ushort4*)(feat + 4 * i);
        float px = bfbits2f(f4.x);
        float py = bfbits2f(f4.y);
        float pz = bfbits2f(f4.z);
        float it = bfbits2f(f4.w);
        int v = inv[i];
        float4 a4 = *(const float4*)&acc4[(long)v * 4];
        float inv_c = 1.0f / a4.x;
        int cz = coors[4*v+1], cy = coors[4*v+2], cx = coors[4*v+3];
        float xv[10];
        xv[0] = px; xv[1] = py; xv[2] = pz;
        xv[3] = px - a4.y * inv_c;
        xv[4] = py - a4.z * inv_c;
        xv[5] = pz - a4.w * inv_c;
        xv[6] = px - ((float)cx * 0.2f + 0.1f + 0.0f);
        xv[7] = py - ((float)cy * 0.2f + 0.1f - 40.0f);
        xv[8] = pz - ((float)cz * 4.0f + 2.0f - 3.0f);
        xv[9] = it;
#pragma unroll
        for (int k = 0; k < 10; k++) xbuf[(long)k * NPTS + i] = xv[k];
        int idx = 0;
#pragma unroll
        for (int a = 0; a < 10; a++) {
            sx[a] += xv[a];
#pragma unroll
            for (int b = 0; b <= a; b++) sxx[idx++] += xv[a] * xv[b];
        }
    }

    // wave reduce 65 scalars, then block-LDS, then global
#pragma unroll
    for (int v = 0; v < 65; v++) {
        float s = (v < 10) ? sx[v] : sxx[v - 10];
        for (int m = 32; m >= 1; m >>= 1) s += __shfl_xor(s, m);
        if ((t & 63) == 0) atomicAdd(&gs[v], s);
    }
    __syncthreads();
    if (t < 65) atomicAdd(&gram[t], gs[t]);
}

// ---- finalize layer-0 BN from Gram ----
__global__ void k_finalize0(const float* __restrict__ gram,
                            const float* __restrict__ W0f,
                            const __hip_bfloat16* __restrict__ gamma,
                            const __hip_bfloat16* __restrict__ beta,
                            float* __restrict__ stats) {
    int c = threadIdx.x;
    if (c >= 64) return;
    float w[10];
#pragma unroll
    for (int k = 0; k < 10; k++) w[k] = W0f[c*10 + k];
    float sum = 0.0f, sq = 0.0f;
#pragma unroll
    for (int a = 0; a < 10; a++) {
        sum += w[a] * gram[a];
        float ta = 0.0f;
#pragma unroll
        for (int b = 0; b < 10; b++) {
            int hi = (a >= b) ? a : b, lo = (a >= b) ? b : a;
            ta += w[b] * gram[10 + hi*(hi+1)/2 + lo];
        }
        sq += w[a] * ta;
    }
    float mu  = sum * (1.0f / NPTS);
    float var = sq * (1.0f / NPTS) - mu * mu;
    float g   = b2f(gamma[c]) * rsqrtf(var + EPSB);
    stats[S_SC0 + c] = g;
    stats[S_BI0 + c] = b2f(beta[c]) - mu * g;
}

// ---- finalize layer-1 BN from partial slots ----
__global__ void k_finalize1(const float* __restrict__ P1,
                            const __hip_bfloat16* __restrict__ gamma,
                            const __hip_bfloat16* __restrict__ beta,
                            float* __restrict__ stats) {
    int c = threadIdx.x;
    if (c >= 64) return;
    float sum = 0.0f, sq = 0.0f;
    for (int s = 0; s < 32; s++) {
        sum += P1[s*128 + c];
        sq  += P1[s*128 + 64 + c];
    }
    float mu  = sum * (1.0f / NPTS);
    float var = sq * (1.0f / NPTS) - mu * mu;
    float g   = b2f(gamma[c]) * rsqrtf(var + EPSB);
    stats[S_SC1 + c] = g;
    stats[S_BI1 + c] = b2f(beta[c]) - mu * g;
}

// ---- K3: h0 = relu(bn0(y0)); LDS transpose -> coalesced atomicMax into v0 ----
// One 64-pt tile per block; N divides exactly; single interior barrier.
__global__ __launch_bounds__(256, 6)
void k_h0max(const float* __restrict__ xbuf,
             const int* __restrict__ inv,
             const float* __restrict__ W0f,
             const float* __restrict__ stats,
             float* __restrict__ v0) {
    __shared__ float ht[64 * HT_LD];
    int t = threadIdx.x, w = t >> 6, l = t & 63;
    int cw = w * 16;
    long base = (long)blockIdx.x * 64;

    float xv[10];
#pragma unroll
    for (int k = 0; k < 10; k++) xv[k] = xbuf[(long)k * NPTS + base + l];
#pragma unroll
    for (int j = 0; j < 16; j++) {
        int c = cw + j;
        float y = 0.0f;
#pragma unroll
        for (int k = 0; k < 10; k++) y += xv[k] * W0f[c*10 + k];
        ht[l * HT_LD + c] = fmaxf(stats[S_SC0 + c] * y + stats[S_BI0 + c], 0.0f);
    }
    __syncthreads();
#pragma unroll
    for (int j = 0; j < 16; j++) {
        int p = w * 16 + j;
        float hv = ht[p * HT_LD + l];
        int vv = inv[base + p];
        atomicMax((unsigned int*)&v0[(long)vv * 64 + l], __float_as_uint(hv));
    }
}

// ---- K4: layer-1 MFMA GEMM, one 64-pt tile/block, ONE barrier.
// Batch stats into 32 partial slots; RAW-y1 segment max straight from the
// MFMA accumulator layout (4 pts x 16 contiguous ch = 4 lines/instr). ----
__global__ __launch_bounds__(256, 6)
void k_mfma_stats(const float* __restrict__ xbuf,
                  const int* __restrict__ inv,
                  const float* __restrict__ W0f,
                  const unsigned short* __restrict__ w1b,
                  const float* __restrict__ stats,
                  const float* __restrict__ v0,
                  float* __restrict__ P1,
                  unsigned int* __restrict__ y1m) {
    __shared__ unsigned short xtb[64 * XTB_LD];
    __shared__ int invs[64];
    int t = threadIdx.x, w = t >> 6, l = t & 63;
    int quad = l >> 4, lm = l & 15;
    long base = (long)blockIdx.x * 64;

    bf16x8 bfrag[4];
    const uint4* wf = (const uint4*)w1b;
#pragma unroll
    for (int ks = 0; ks < 4; ks++)
        bfrag[ks] = __builtin_bit_cast(bf16x8, wf[(w * 4 + ks) * 64 + l]);

    // ---- stage x1 tile (bf16 [pt][k]) ----
    {
        int cw = w * 16;
        float xv[10];
#pragma unroll
        for (int k = 0; k < 10; k++) xv[k] = xbuf[(long)k * NPTS + base + l];
#pragma unroll
        for (int jj = 0; jj < 8; jj++) {
            int c0 = cw + 2 * jj, c1 = c0 + 1;
            float ya = 0.0f, yb = 0.0f;
#pragma unroll
            for (int k = 0; k < 10; k++) {
                ya += xv[k] * W0f[c0*10 + k];
                yb += xv[k] * W0f[c1*10 + k];
            }
            float ha = fmaxf(stats[S_SC0 + c0] * ya + stats[S_BI0 + c0], 0.0f);
            float hb = fmaxf(stats[S_SC0 + c1] * yb + stats[S_BI0 + c1], 0.0f);
            unsigned int pk = (unsigned int)bf16u(ha) | ((unsigned int)bf16u(hb) << 16);
            *(unsigned int*)&xtb[l * XTB_LD + c0] = pk;
        }
    }
    {
        int p = t >> 2, q = t & 3;
        int vv = inv[base + p];
        const float4* src = (const float4*)&v0[(long)vv * 64 + q * 16];
#pragma unroll
        for (int u = 0; u < 4; u++) {
            float4 f4 = src[u];
            ushort4 s4 = { bf16u(f4.x), bf16u(f4.y), bf16u(f4.z), bf16u(f4.w) };
            *(ushort4*)&xtb[p * XTB_LD + 64 + q * 16 + 4 * u] = s4;
        }
    }
    if (t < 64) invs[t] = inv[base + t];
    __syncthreads();

    // ---- MFMA ----
    f32x4 acc[4];
#pragma unroll
    for (int pg = 0; pg < 4; pg++) acc[pg] = (f32x4){0.f, 0.f, 0.f, 0.f};
#pragma unroll
    for (int ks = 0; ks < 4; ks++) {
#pragma unroll
        for (int pg = 0; pg < 4; pg++) {
            const uint4* ap = (const uint4*)&xtb[(pg * 16 + lm) * XTB_LD + ks * 32 + quad * 8];
            bf16x8 a = __builtin_bit_cast(bf16x8, *ap);
            acc[pg] = __builtin_amdgcn_mfma_f32_16x16x32_bf16(a, bfrag[ks], acc[pg], 0, 0, 0);
        }
    }

    // ---- stats + direct coalesced atomicMax from accumulator layout ----
    float ssum = 0.0f, ssq = 0.0f;
#pragma unroll
    for (int pg = 0; pg < 4; pg++) {
#pragma unroll
        for (int r = 0; r < 4; r++) {
            float y = acc[pg][r];
            ssum += y; ssq += y * y;
            int p = pg * 16 + quad * 4 + r;        // C layout: row=quad*4+r, col=lm
            int vv = invs[p];
            atomicMax(&y1m[(long)vv * 64 + w * 16 + lm], fkey(y));
        }
    }
    ssum += __shfl_xor(ssum, 16); ssq += __shfl_xor(ssq, 16);
    ssum += __shfl_xor(ssum, 32); ssq += __shfl_xor(ssq, 32);
    if (l < 16) {
        int slot = blockIdx.x & 31;
        atomicAdd(&P1[slot * 128 + w * 16 + lm], ssum);
        atomicAdd(&P1[slot * 128 + 64 + w * 16 + lm], ssq);
    }
}

// ---- K5: emit output: feats = relu(bn1(decode(y1max))), then bf16-rounded coors ----
__global__ void k_out(const unsigned int* __restrict__ y1m,
                      const float* __restrict__ stats,
                      const int* __restrict__ coors,
                      float* __restrict__ out) {
    long t = (long)blockIdx.x * 256 + threadIdx.x;
    const long nfeat = (long)NVOX * 64;
    if (t < nfeat) {
        int c = (int)(t & 63);
        float y = funkey(y1m[t]);
        out[t] = fmaxf(stats[S_SC1 + c] * y + stats[S_BI1 + c], 0.0f);
    } else if (t < nfeat + (long)NVOX * 4) {
        out[t] = b2f(__float2bfloat16((float)coors[t - nfeat]));
    }
}

extern "C" void kernel_launch(void* const* d_in, const int* in_sizes, int n_in,
                              void* d_out, int out_size, void* d_ws, size_t ws_size,
                              hipStream_t stream) {
    const __hip_bfloat16* feat = (const __hip_bfloat16*)d_in[0];
    const __hip_bfloat16* W0   = (const __hip_bfloat16*)d_in[1];
    const __hip_bfloat16* g0   = (const __hip_bfloat16*)d_in[2];
    const __hip_bfloat16* be0  = (const __hip_bfloat16*)d_in[3];
    const __hip_bfloat16* W1   = (const __hip_bfloat16*)d_in[4];
    const __hip_bfloat16* g1   = (const __hip_bfloat16*)d_in[5];
    const __hip_bfloat16* be1  = (const __hip_bfloat16*)d_in[6];
    const int* inv   = (const int*)d_in[7];
    const int* coors = (const int*)d_in[8];
    float* out = (float*)d_out;

    float* ws    = (float*)d_ws;
    float* acc4  = ws + OFF_ACC4;
    float* gram  = ws + OFF_GRAM;
    float* stats = ws + OFF_STATS;
    float* P1    = ws + OFF_P1;
    float* v0    = ws + OFF_V0;
    unsigned int* y1m = (unsigned int*)(ws + OFF_Y1M);
    float* xbuf  = ws + OFF_X;
    float* W0f   = ws + OFF_W0F;
    unsigned short* w1b = (unsigned short*)(ws + OFF_W1B);

    hipMemsetAsync(ws, 0, (size_t)ZERO_FLOATS * sizeof(float), stream);

    k_wconv<<<1, 256, 0, stream>>>(W0, W1, W0f, w1b);
    k_vsum<<<(4 * NPTS + 255) / 256, 256, 0, stream>>>(feat, inv, acc4);
    k_feat_gram<<<GBLK, 256, 0, stream>>>(feat, inv, coors, acc4, xbuf, gram);
    k_finalize0<<<1, 64, 0, stream>>>(gram, W0f, g0, be0, stats);
    k_h0max<<<NTILE, 256, 0, stream>>>(xbuf, inv, W0f, stats, v0);
    k_mfma_stats<<<NTILE, 256, 0, stream>>>(xbuf, inv, W0f, w1b, stats, v0, P1, y1m);
    k_finalize1<<<1, 64, 0, stream>>>(P1, g1, be1, stats);

    const long nout = (long)NVOX * 64 + (long)NVOX * 4;
    k_out<<<(int)((nout + 255) / 256), 256, 0, stream>>>(y1m, stats, coors, out);
}

// Round 8
// 293.823 us; speedup vs baseline: 9.4580x; 1.4015x over previous
//
#include <hip/hip_runtime.h>
#include <hip/hip_bf16.h>

// Problem constants (match reference)
#define NPTS 400000          // == 6250 * 64 exactly (no tile tails)
#define NVOX 100000
#define EPSB 1e-3f
#define NTILE 6250
#define NBLK_SCAN 391        // ceil(NVOX/256)

// ws layout (in floats) — total ~56.8 MB (known-safe: round 2-7 used ~69 MB)
#define OFF_ACC4  0                        // 4*NVOX interleaved [cnt,sx,sy,sz]
#define OFF_GRAM  (4*NVOX)                 // 72: sx[10]+sxx[55]
#define OFF_STATS (OFF_GRAM + 72)          // 256: sc0|bi0|sc1|bi1
#define OFF_P1    (OFF_STATS + 256)        // 32 slots * 128
#define OFF_V0    (OFF_P1 + 4096)          // NVOX*64 (h0 max, plain uint keys)
#define OFF_Y1M   (OFF_V0 + NVOX*64)       // NVOX*64 (raw y1 max, orderable keys)
#define ZERO_FLOATS (OFF_Y1M + NVOX*64)
#define OFF_VTMP  ZERO_FLOATS              // NVOX ints (per-voxel local scan)
#define OFF_BSUM  (OFF_VTMP + NVOX)        // 512 ints
#define OFF_VOFF  (OFF_BSUM + 512)         // NVOX ints (scatter cursors)
#define OFF_ORD   (OFF_VOFF + NVOX)        // NPTS ints (points sorted by voxel)
#define OFF_VS    (OFF_ORD + NPTS)         // NPTS ints (vsorted, non-decreasing)
#define OFF_W0F   (OFF_VS + NPTS)          // 640
#define OFF_W1B   (OFF_W0F + 640)          // 4096 floats = 8192 bf16

// stats sub-offsets
#define S_SC0 0
#define S_BI0 64
#define S_SC1 128
#define S_BI1 192

#define XTB_LD 136
#define HT_LD  65
#define GBLK 782

typedef __bf16 bf16x8 __attribute__((ext_vector_type(8)));
typedef float  f32x4  __attribute__((ext_vector_type(4)));

__device__ __forceinline__ float b2f(__hip_bfloat16 h) { return __bfloat162float(h); }
__device__ __forceinline__ float bfbits2f(unsigned short u) {
    return __uint_as_float((unsigned int)u << 16);
}
__device__ __forceinline__ unsigned short bf16u(float f) {
    __hip_bfloat16 h = __float2bfloat16(f);
    return __builtin_bit_cast(unsigned short, h);
}
__device__ __forceinline__ unsigned int fkey(float f) {
    unsigned int u = __float_as_uint(f);
    return (u & 0x80000000u) ? ~u : (u | 0x80000000u);
}
__device__ __forceinline__ float funkey(unsigned int k) {
    unsigned int u = (k & 0x80000000u) ? (k & 0x7FFFFFFFu) : ~k;
    return __uint_as_float(u);
}

// per-point 10-feature vector from raw inputs (replaces xbuf)
__device__ __forceinline__ void compute_x(const __hip_bfloat16* __restrict__ feat,
                                          const float* __restrict__ acc4,
                                          const int* __restrict__ coors,
                                          long i, int v, float* xv) {
    ushort4 f4 = *(const ushort4*)(feat + 4 * i);
    float px = bfbits2f(f4.x), py = bfbits2f(f4.y), pz = bfbits2f(f4.z), it = bfbits2f(f4.w);
    float4 a4 = *(const float4*)&acc4[4 * (long)v];
    float ic = 1.0f / a4.x;
    int4 c4 = *(const int4*)&coors[4 * (long)v];   // (b, z, y, x)
    xv[0] = px; xv[1] = py; xv[2] = pz;
    xv[3] = px - a4.y * ic; xv[4] = py - a4.z * ic; xv[5] = pz - a4.w * ic;
    xv[6] = px - ((float)c4.w * 0.2f + 0.1f);
    xv[7] = py - ((float)c4.z * 0.2f + 0.1f - 40.0f);
    xv[8] = pz - ((float)c4.y * 4.0f + 2.0f - 3.0f);
    xv[9] = it;
}

// ---- K0: W0 -> fp32; W1 -> bf16 MFMA B-fragment order ----
__global__ void k_wconv(const __hip_bfloat16* __restrict__ W0,
                        const __hip_bfloat16* __restrict__ W1,
                        float* __restrict__ W0f, unsigned short* __restrict__ w1b) {
    int t = threadIdx.x;
    for (int j = t; j < 640; j += 256) W0f[j] = b2f(W0[j]);
    for (int f = t; f < 8192; f += 256) {
        int j  = f & 7;
        int l  = (f >> 3) & 63;
        int ks = (f >> 9) & 3;
        int ct = f >> 11;
        int ch = ct * 16 + (l & 15);
        int k  = ks * 32 + ((l >> 4) & 3) * 8 + j;
        w1b[f] = __builtin_bit_cast(unsigned short, W1[ch * 128 + k]);
    }
}

// ---- K1: per-voxel count + xyz sums (4-lane coalesced atomics) ----
__global__ void k_vsum(const __hip_bfloat16* __restrict__ feat,
                       const int* __restrict__ inv,
                       float* __restrict__ acc4) {
    long t = (long)blockIdx.x * 256 + threadIdx.x;
    int pt = (int)(t >> 2);
    int comp = (int)(t & 3);
    if (pt >= NPTS) return;
    float val = (comp == 0) ? 1.0f : b2f(feat[4 * pt + comp - 1]);
    int v = inv[pt];
    atomicAdd(&acc4[(long)v * 4 + comp], val);
}

// ---- prefix scan of voxel counts (3 kernels) ----
__global__ void k_scan1(const float* __restrict__ acc4,
                        int* __restrict__ vtmp, int* __restrict__ bsum) {
    __shared__ int sc[256];
    int b = blockIdx.x, t = threadIdx.x;
    int v = b * 256 + t;
    int c = (v < NVOX) ? (int)acc4[4 * (long)v] : 0;
    sc[t] = c;
    __syncthreads();
    int val = c;
    for (int off = 1; off < 256; off <<= 1) {
        int x = (t >= off) ? sc[t - off] : 0;
        __syncthreads();
        val += x; sc[t] = val;
        __syncthreads();
    }
    if (v < NVOX) vtmp[v] = val - c;
    if (t == 255) bsum[b] = val;
}

__global__ void k_scan2(int* __restrict__ bsum) {
    __shared__ int sc[512];
    int t = threadIdx.x;
    int c = (t < NBLK_SCAN) ? bsum[t] : 0;
    sc[t] = c;
    __syncthreads();
    int val = c;
    for (int off = 1; off < 512; off <<= 1) {
        int x = (t >= off) ? sc[t - off] : 0;
        __syncthreads();
        val += x; sc[t] = val;
        __syncthreads();
    }
    if (t < NBLK_SCAN) bsum[t] = val - c;
}

__global__ void k_scan3(const int* __restrict__ vtmp, const int* __restrict__ bsum,
                        int* __restrict__ voff) {
    int v = blockIdx.x * 256 + threadIdx.x;
    if (v < NVOX) voff[v] = vtmp[v] + bsum[v >> 8];
}

// ---- K2: fused Gram stats + counting-sort scatter (original order, coalesced) ----
__global__ __launch_bounds__(256, 4)
void k_prep(const __hip_bfloat16* __restrict__ feat,
            const int* __restrict__ inv,
            const int* __restrict__ coors,
            const float* __restrict__ acc4,
            int* __restrict__ voff,
            int* __restrict__ ord, int* __restrict__ vsorted,
            float* __restrict__ gram) {
    __shared__ float gs[72];
    int t = threadIdx.x;
    if (t < 72) gs[t] = 0.0f;
    __syncthreads();

    float sx[10], sxx[55];
#pragma unroll
    for (int a = 0; a < 10; a++) sx[a] = 0.0f;
#pragma unroll
    for (int a = 0; a < 55; a++) sxx[a] = 0.0f;

    for (long i = (long)blockIdx.x * 256 + t; i < NPTS; i += (long)GBLK * 256) {
        int v = inv[i];
        float xv[10];
        compute_x(feat, acc4, coors, i, v, xv);
        int idx = 0;
#pragma unroll
        for (int a = 0; a < 10; a++) {
            sx[a] += xv[a];
#pragma unroll
            for (int b = 0; b <= a; b++) sxx[idx++] += xv[a] * xv[b];
        }
        int pos = atomicAdd(&voff[v], 1);
        ord[pos] = (int)i;
        vsorted[pos] = v;
    }

#pragma unroll
    for (int v = 0; v < 65; v++) {
        float s = (v < 10) ? sx[v] : sxx[v - 10];
        for (int m = 32; m >= 1; m >>= 1) s += __shfl_xor(s, m);
        if ((t & 63) == 0) atomicAdd(&gs[v], s);
    }
    __syncthreads();
    if (t < 65) atomicAdd(&gram[t], gs[t]);
}

// ---- finalize layer-0 BN from Gram ----
__global__ void k_finalize0(const float* __restrict__ gram,
                            const float* __restrict__ W0f,
                            const __hip_bfloat16* __restrict__ gamma,
                            const __hip_bfloat16* __restrict__ beta,
                            float* __restrict__ stats) {
    int c = threadIdx.x;
    if (c >= 64) return;
    float w[10];
#pragma unroll
    for (int k = 0; k < 10; k++) w[k] = W0f[c*10 + k];
    float sum = 0.0f, sq = 0.0f;
#pragma unroll
    for (int a = 0; a < 10; a++) {
        sum += w[a] * gram[a];
        float ta = 0.0f;
#pragma unroll
        for (int b = 0; b < 10; b++) {
            int hi = (a >= b) ? a : b, lo = (a >= b) ? b : a;
            ta += w[b] * gram[10 + hi*(hi+1)/2 + lo];
        }
        sq += w[a] * ta;
    }
    float mu  = sum * (1.0f / NPTS);
    float var = sq * (1.0f / NPTS) - mu * mu;
    float g   = b2f(gamma[c]) * rsqrtf(var + EPSB);
    stats[S_SC0 + c] = g;
    stats[S_BI0 + c] = b2f(beta[c]) - mu * g;
}

// ---- finalize layer-1 BN from partial slots ----
__global__ void k_finalize1(const float* __restrict__ P1,
                            const __hip_bfloat16* __restrict__ gamma,
                            const __hip_bfloat16* __restrict__ beta,
                            float* __restrict__ stats) {
    int c = threadIdx.x;
    if (c >= 64) return;
    float sum = 0.0f, sq = 0.0f;
    for (int s = 0; s < 32; s++) {
        sum += P1[s*128 + c];
        sq  += P1[s*128 + 64 + c];
    }
    float mu  = sum * (1.0f / NPTS);
    float var = sq * (1.0f / NPTS) - mu * mu;
    float g   = b2f(gamma[c]) * rsqrtf(var + EPSB);
    stats[S_SC1 + c] = g;
    stats[S_BI1 + c] = b2f(beta[c]) - mu * g;
}

// ---- K3: h0 max over SORTED points, run-combined atomics ----
__global__ __launch_bounds__(256, 6)
void k_h0max(const int* __restrict__ ord, const int* __restrict__ vsorted,
             const __hip_bfloat16* __restrict__ feat,
             const float* __restrict__ acc4, const int* __restrict__ coors,
             const float* __restrict__ W0f, const float* __restrict__ stats,
             float* __restrict__ v0) {
    __shared__ float ht[64 * HT_LD];
    __shared__ int invs[64];
    int t = threadIdx.x, w = t >> 6, l = t & 63;
    long base = (long)blockIdx.x * 64;
    long s = base + l;
    int i = ord[s];
    int v = vsorted[s];
    if (w == 0) invs[l] = v;

    float xv[10];
    compute_x(feat, acc4, coors, (long)i, v, xv);
    int cw = w * 16;
#pragma unroll
    for (int j = 0; j < 16; j++) {
        int c = cw + j;
        float y = 0.0f;
#pragma unroll
        for (int k = 0; k < 10; k++) y += xv[k] * W0f[c*10 + k];
        ht[l * HT_LD + c] = fmaxf(stats[S_SC0 + c] * y + stats[S_BI0 + c], 0.0f);
    }
    __syncthreads();
    // lane = channel; walk 16 sorted points, combine same-voxel runs
    float m = 0.0f;
#pragma unroll
    for (int j = 0; j < 16; j++) {
        int p = cw + j;
        m = fmaxf(m, ht[p * HT_LD + l]);
        if (j == 15 || invs[p + 1] != invs[p]) {
            atomicMax((unsigned int*)&v0[(long)invs[p] * 64 + l], __float_as_uint(m));
            m = 0.0f;
        }
    }
}

// ---- K4: layer-1 MFMA GEMM over SORTED points; run-combined raw-y1 atomics ----
__global__ __launch_bounds__(256, 6)
void k_mfma_stats(const int* __restrict__ ord, const int* __restrict__ vsorted,
                  const __hip_bfloat16* __restrict__ feat,
                  const float* __restrict__ acc4, const int* __restrict__ coors,
                  const float* __restrict__ W0f,
                  const unsigned short* __restrict__ w1b,
                  const float* __restrict__ stats,
                  const float* __restrict__ v0,
                  float* __restrict__ P1,
                  unsigned int* __restrict__ y1m) {
    __shared__ union {
        unsigned short xtb[64 * XTB_LD];
        float ht[64 * HT_LD];
    } sm;
    __shared__ int invs[64];
    int t = threadIdx.x, w = t >> 6, l = t & 63;
    int quad = l >> 4, lm = l & 15;
    long base = (long)blockIdx.x * 64;
    long s = base + l;
    int i = ord[s];
    int v = vsorted[s];
    if (w == 0) invs[l] = v;

    bf16x8 bfrag[4];
    const uint4* wf = (const uint4*)w1b;
#pragma unroll
    for (int ks = 0; ks < 4; ks++)
        bfrag[ks] = __builtin_bit_cast(bf16x8, wf[(w * 4 + ks) * 64 + l]);

    // ---- stage x1 tile (bf16 [pt][k]) ----
    {
        int cw = w * 16;
        float xv[10];
        compute_x(feat, acc4, coors, (long)i, v, xv);
#pragma unroll
        for (int jj = 0; jj < 8; jj++) {
            int c0 = cw + 2 * jj, c1 = c0 + 1;
            float ya = 0.0f, yb = 0.0f;
#pragma unroll
            for (int k = 0; k < 10; k++) {
                ya += xv[k] * W0f[c0*10 + k];
                yb += xv[k] * W0f[c1*10 + k];
            }
            float ha = fmaxf(stats[S_SC0 + c0] * ya + stats[S_BI0 + c0], 0.0f);
            float hb = fmaxf(stats[S_SC0 + c1] * yb + stats[S_BI0 + c1], 0.0f);
            unsigned int pk = (unsigned int)bf16u(ha) | ((unsigned int)bf16u(hb) << 16);
            *(unsigned int*)&sm.xtb[l * XTB_LD + c0] = pk;
        }
    }
    {
        int p = t >> 2, q = t & 3;
        int vv = vsorted[base + p];       // sorted -> consecutive rows L1-hot
        const float4* src = (const float4*)&v0[(long)vv * 64 + q * 16];
#pragma unroll
        for (int u = 0; u < 4; u++) {
            float4 f4 = src[u];
            ushort4 s4 = { bf16u(f4.x), bf16u(f4.y), bf16u(f4.z), bf16u(f4.w) };
            *(ushort4*)&sm.xtb[p * XTB_LD + 64 + q * 16 + 4 * u] = s4;
        }
    }
    __syncthreads();

    // ---- MFMA ----
    f32x4 acc[4];
#pragma unroll
    for (int pg = 0; pg < 4; pg++) acc[pg] = (f32x4){0.f, 0.f, 0.f, 0.f};
#pragma unroll
    for (int ks = 0; ks < 4; ks++) {
#pragma unroll
        for (int pg = 0; pg < 4; pg++) {
            const uint4* ap = (const uint4*)&sm.xtb[(pg * 16 + lm) * XTB_LD + ks * 32 + quad * 8];
            bf16x8 a = __builtin_bit_cast(bf16x8, *ap);
            acc[pg] = __builtin_amdgcn_mfma_f32_16x16x32_bf16(a, bfrag[ks], acc[pg], 0, 0, 0);
        }
    }

    // ---- stats from accumulators ----
    float ssum = 0.0f, ssq = 0.0f;
#pragma unroll
    for (int pg = 0; pg < 4; pg++) {
#pragma unroll
        for (int r = 0; r < 4; r++) {
            float y = acc[pg][r];
            ssum += y; ssq += y * y;
        }
    }
    __syncthreads();   // all xtb reads done -> safe to overwrite with ht

    // raw y1 -> LDS transpose (C layout: row = quad*4+r, col = lm)
#pragma unroll
    for (int pg = 0; pg < 4; pg++) {
#pragma unroll
        for (int r = 0; r < 4; r++)
            sm.ht[(pg * 16 + quad * 4 + r) * HT_LD + w * 16 + lm] = acc[pg][r];
    }
    __syncthreads();

    // lane = channel; walk 16 sorted points, combine same-voxel runs
    float m = -3.402823e38f;
    int cw = w * 16;
#pragma unroll
    for (int j = 0; j < 16; j++) {
        int p = cw + j;
        m = fmaxf(m, sm.ht[p * HT_LD + l]);
        if (j == 15 || invs[p + 1] != invs[p]) {
            atomicMax(&y1m[(long)invs[p] * 64 + l], fkey(m));
            m = -3.402823e38f;
        }
    }

    ssum += __shfl_xor(ssum, 16); ssq += __shfl_xor(ssq, 16);
    ssum += __shfl_xor(ssum, 32); ssq += __shfl_xor(ssq, 32);
    if (l < 16) {
        int slot = blockIdx.x & 31;
        atomicAdd(&P1[slot * 128 + w * 16 + lm], ssum);
        atomicAdd(&P1[slot * 128 + 64 + w * 16 + lm], ssq);
    }
}

// ---- K5: emit output: feats = relu(bn1(decode(y1max))), then bf16-rounded coors ----
__global__ void k_out(const unsigned int* __restrict__ y1m,
                      const float* __restrict__ stats,
                      const int* __restrict__ coors,
                      float* __restrict__ out) {
    long t = (long)blockIdx.x * 256 + threadIdx.x;
    const long nfeat = (long)NVOX * 64;
    if (t < nfeat) {
        int c = (int)(t & 63);
        float y = funkey(y1m[t]);
        out[t] = fmaxf(stats[S_SC1 + c] * y + stats[S_BI1 + c], 0.0f);
    } else if (t < nfeat + (long)NVOX * 4) {
        out[t] = b2f(__float2bfloat16((float)coors[t - nfeat]));
    }
}

extern "C" void kernel_launch(void* const* d_in, const int* in_sizes, int n_in,
                              void* d_out, int out_size, void* d_ws, size_t ws_size,
                              hipStream_t stream) {
    const __hip_bfloat16* feat = (const __hip_bfloat16*)d_in[0];
    const __hip_bfloat16* W0   = (const __hip_bfloat16*)d_in[1];
    const __hip_bfloat16* g0   = (const __hip_bfloat16*)d_in[2];
    const __hip_bfloat16* be0  = (const __hip_bfloat16*)d_in[3];
    const __hip_bfloat16* W1   = (const __hip_bfloat16*)d_in[4];
    const __hip_bfloat16* g1   = (const __hip_bfloat16*)d_in[5];
    const __hip_bfloat16* be1  = (const __hip_bfloat16*)d_in[6];
    const int* inv   = (const int*)d_in[7];
    const int* coors = (const int*)d_in[8];
    float* out = (float*)d_out;

    float* ws    = (float*)d_ws;
    float* acc4  = ws + OFF_ACC4;
    float* gram  = ws + OFF_GRAM;
    float* stats = ws + OFF_STATS;
    float* P1    = ws + OFF_P1;
    float* v0    = ws + OFF_V0;
    unsigned int* y1m = (unsigned int*)(ws + OFF_Y1M);
    int* vtmp    = (int*)(ws + OFF_VTMP);
    int* bsum    = (int*)(ws + OFF_BSUM);
    int* voff    = (int*)(ws + OFF_VOFF);
    int* ord     = (int*)(ws + OFF_ORD);
    int* vsorted = (int*)(ws + OFF_VS);
    float* W0f   = ws + OFF_W0F;
    unsigned short* w1b = (unsigned short*)(ws + OFF_W1B);

    hipMemsetAsync(ws, 0, (size_t)ZERO_FLOATS * sizeof(float), stream);

    k_wconv<<<1, 256, 0, stream>>>(W0, W1, W0f, w1b);
    k_vsum<<<(4 * NPTS + 255) / 256, 256, 0, stream>>>(feat, inv, acc4);
    k_scan1<<<NBLK_SCAN, 256, 0, stream>>>(acc4, vtmp, bsum);
    k_scan2<<<1, 512, 0, stream>>>(bsum);
    k_scan3<<<NBLK_SCAN, 256, 0, stream>>>(vtmp, bsum, voff);
    k_prep<<<GBLK, 256, 0, stream>>>(feat, inv, coors, acc4, voff, ord, vsorted, gram);
    k_finalize0<<<1, 64, 0, stream>>>(gram, W0f, g0, be0, stats);
    k_h0max<<<NTILE, 256, 0, stream>>>(ord, vsorted, feat, acc4, coors, W0f, stats, v0);
    k_mfma_stats<<<NTILE, 256, 0, stream>>>(ord, vsorted, feat, acc4, coors,
                                            W0f, w1b, stats, v0, P1, y1m);
    k_finalize1<<<1, 64, 0, stream>>>(P1, g1, be1, stats);

    const long nout = (long)NVOX * 64 + (long)NVOX * 4;
    k_out<<<(int)((nout + 255) / 256), 256, 0, stream>>>(y1m, stats, coors, out);
}